// Round 1
// 208.149 us; speedup vs baseline: 1.0155x; 1.0155x over previous
//
#include <hip/hip_runtime.h>
#include <cstdint>
#include <cstddef>

// ---------------- problem constants (fixed by setup_inputs) ----------------
#define B_  4
#define T_  2048
#define D_  512
#define NH_ 8
#define HD_ 64
#define FF_ 2048
#define M_  (B_*T_)   // 8192 token rows

typedef unsigned short u16;
typedef __attribute__((ext_vector_type(8))) unsigned short u16x8;
typedef __attribute__((ext_vector_type(8))) __bf16         bf16x8;
typedef __attribute__((ext_vector_type(4))) float          f32x4;

__device__ __forceinline__ u16 f2bf(float f) {            // RNE f32 -> bf16
  unsigned u = __float_as_uint(f);
  u += 0x7FFF + ((u >> 16) & 1);
  return (u16)(u >> 16);
}
__device__ __forceinline__ float bf2f(u16 h) {
  return __uint_as_float((unsigned)h << 16);
}

__device__ __forceinline__ f32x4 mfma_bf16(u16x8 a, u16x8 b, f32x4 c) {
  return __builtin_amdgcn_mfma_f32_16x16x32_bf16(
      __builtin_bit_cast(bf16x8, a), __builtin_bit_cast(bf16x8, b), c, 0, 0, 0);
}

// async global->LDS, 16B per lane; LDS dest = wave-uniform base + lane*16
__device__ __forceinline__ void async16(const void* g, void* l) {
  __builtin_amdgcn_global_load_lds(
      (const __attribute__((address_space(1))) unsigned int*)g,
      (__attribute__((address_space(3))) unsigned int*)l, 16, 0, 0);
}

// Branchless GELU via A&S 7.1.26 erf (|err| <= 1.5e-7).
__device__ __forceinline__ float gelu_f(float v) {
  float ax = fabsf(v) * 0.70710678118f;
  float t = 1.0f / (1.0f + 0.3275911f * ax);
  float p = ((((1.061405429f * t - 1.453152027f) * t + 1.421413741f) * t
              - 0.284496736f) * t + 0.254829592f) * t;
  float e = __expf(-ax * ax);
  float er = 1.0f - p * e;
  float s = (v >= 0.0f) ? er : -er;
  return 0.5f * v * (1.0f + s);
}

// ---- fused prep: 4 weight transposes (norm weights FOLDED into wqkv/w1)
// + x->bf16 + per-row inv-rms + sumsq zeroing, in ONE launch.
// blocks 0..3071: transpose tiles; 3072..5119: row pass; 5120..5151: zero ss.
__global__ __launch_bounds__(256) void prep_kernel(
    const float* __restrict__ i0, u16* __restrict__ o0,   // wqkv 512x1536
    const float* __restrict__ i1, u16* __restrict__ o1,   // wout 512x512
    const float* __restrict__ i2, u16* __restrict__ o2,   // w1   512x2048
    const float* __restrict__ i3, u16* __restrict__ o3,   // w2   2048x512
    const float* __restrict__ x, const float* __restrict__ n1w,
    const float* __restrict__ n2w,
    float* __restrict__ inv, u16* __restrict__ xbf, float* __restrict__ ssz) {
  __shared__ float tile[32][33];
  const int bid = blockIdx.x, tid = threadIdx.x;
  if (bid < 3072) {
    const float* in; u16* out; const float* sc; int R, C, gx, lb;
    if (bid < 768)       { in = i0; out = o0; R = 512;  C = 1536; gx = 48; lb = bid;        sc = n1w; }
    else if (bid < 1024) { in = i1; out = o1; R = 512;  C = 512;  gx = 16; lb = bid - 768;  sc = nullptr; }
    else if (bid < 2048) { in = i2; out = o2; R = 512;  C = 2048; gx = 64; lb = bid - 1024; sc = n2w; }
    else                 { in = i3; out = o3; R = 2048; C = 512;  gx = 16; lb = bid - 2048; sc = nullptr; }
    int c0 = (lb % gx) * 32, r0 = (lb / gx) * 32;
    int tx = tid & 31, ty = tid >> 5;  // 32x8
#pragma unroll
    for (int i = 0; i < 4; i++)
      tile[ty + i * 8][tx] = in[(size_t)(r0 + ty + i * 8) * C + c0 + tx];
    __syncthreads();
    float s = sc ? sc[r0 + tx] : 1.0f;   // k-index = r0+tx after transpose
#pragma unroll
    for (int i = 0; i < 4; i++)
      out[(size_t)(c0 + ty + i * 8) * R + r0 + tx] = f2bf(tile[tx][ty + i * 8] * s);
  } else if (bid < 5120) {
    int row  = (bid - 3072) * 4 + (tid >> 6);
    int lane = tid & 63;
    const float* xr = x + (size_t)row * D_ + lane * 8;
    float v[8];
    *(float4*)(v)     = *(const float4*)xr;
    *(float4*)(v + 4) = *(const float4*)(xr + 4);
    u16 rw[8];
#pragma unroll
    for (int e = 0; e < 8; e++) rw[e] = f2bf(v[e]);
    *(uint4*)(xbf + (size_t)row * D_ + lane * 8) = *(uint4*)rw;
    float ss = 0.f;
#pragma unroll
    for (int e = 0; e < 8; e++) ss += v[e] * v[e];
#pragma unroll
    for (int m = 1; m < 64; m <<= 1) ss += __shfl_xor(ss, m, 64);
    if (lane == 0) inv[row] = rsqrtf(ss * (1.0f / D_) + 1e-6f);
  } else {
    ssz[(bid - 5120) * 256 + tid] = 0.f;   // 32*256 = 8192 rows
  }
}

// ---- bf16 MFMA GEMM: C[M,N] = A[M,K] * Bt[N,K]^T (+rowscale)(+bias)(gelu)(+res)
// BM x BN tile, BK=64, double-buffered LDS, prefetch-after-barrier.
// XOR-swizzled LDS: 16B chunk c (of 8) of row r at physical slot c^(r&7).
// RES_MODE: 0 none, 1 f32, 2 bf16.
// SCALE_MODE (applied to acc BEFORE bias): 0 none, 1 v*=rowscale[rg],
//   2 v*=rsqrt(rowscale[rg]/512+eps)  (fused rmsnorm; norm weight folded in Bt).
// EMIT_SS: per-row partial sum of squares of FINAL value -> atomicAdd(ssout).
template <int BM, int BN, bool HAS_BIAS, int RES_MODE, bool DO_GELU,
          bool STORE_BF16, int SCALE_MODE, bool EMIT_SS>
__global__ __launch_bounds__(256) void gemm_kernel(
    const u16* __restrict__ A, const u16* __restrict__ Bt, void* __restrict__ Cv,
    const float* __restrict__ bias, const void* __restrict__ resv,
    const float* __restrict__ rowscale, float* __restrict__ ssout,
    int M, int N, int K) {
  constexpr int ACH = BM / 32;              // A staging chunks (32 rows each)
  constexpr int BCH = BN / 32;              // B staging chunks
  constexpr int WM  = BM / 2, WN = BN / 2;  // per-wave tile
  constexpr int MI  = WM / 16, NJ = WN / 16;
  constexpr int EW  = BN + 4;               // epilogue LDS row pitch (f32)
  constexpr int STG = (BM + BN) * 128;      // bytes per stage buffer (A+B)
  constexpr int EPB = 32 * EW * 4;          // epilogue bytes
  constexpr int SMB = (2 * STG > EPB) ? 2 * STG : EPB;
  __shared__ __align__(16) char smem[SMB];
  const int tid = threadIdx.x;
  const int lane = tid & 63, w = tid >> 6;
  const int quad = lane >> 4, m16 = lane & 15;
  const int wm = w & 1, wn = w >> 1;
  const int m0 = blockIdx.y * BM, n0 = blockIdx.x * BN;

  f32x4 acc[MI][NJ];
#pragma unroll
  for (int i = 0; i < MI; i++)
#pragma unroll
    for (int j = 0; j < NJ; j++) acc[i][j] = (f32x4){0.f, 0.f, 0.f, 0.f};

  const int srow = tid >> 3;                       // 0..31
  const int scol = (((tid & 7) ^ (srow & 7))) * 8; // swizzled source k-chunk
  const u16* Ag = A  + (size_t)(m0 + srow) * K + scol;
  const u16* Bg = Bt + (size_t)(n0 + srow) * K + scol;

  auto stage = [&](int buf, int kt) {
    char* base = smem + buf * STG;
#pragma unroll
    for (int c = 0; c < ACH; c++)
      async16(Ag + (size_t)c * 32 * K + kt, base + c * 4096 + tid * 16);
#pragma unroll
    for (int c = 0; c < BCH; c++)
      async16(Bg + (size_t)c * 32 * K + kt, base + BM * 128 + c * 4096 + tid * 16);
  };
  auto compute = [&](int buf) {
    const u16* lA = (const u16*)(smem + buf * STG);
    const u16* lB = (const u16*)(smem + buf * STG + BM * 128);
#pragma unroll
    for (int kk = 0; kk < 2; kk++) {
      const int sl = ((kk * 4 + quad) ^ (m16 & 7)) * 8;  // physical slot
      const u16* pa = lA + (wm * WM + m16) * 64 + sl;
      const u16* pb = lB + (wn * WN + m16) * 64 + sl;
      u16x8 af[MI], bfr[NJ];
#pragma unroll
      for (int i = 0; i < MI; i++) af[i] = *(const u16x8*)(pa + i * 1024);
#pragma unroll
      for (int j = 0; j < NJ; j++) bfr[j] = *(const u16x8*)(pb + j * 1024);
#pragma unroll
      for (int i = 0; i < MI; i++)
#pragma unroll
        for (int j = 0; j < NJ; j++)
          acc[i][j] = mfma_bf16(af[i], bfr[j], acc[i][j]);
    }
  };

  const int nk = K >> 6;
  stage(0, 0);
  for (int t = 0; t < nk; t++) {
    __syncthreads();                // drains stage(t); covered by compute(t-1)
    if (t + 1 < nk) stage((t + 1) & 1, (t + 1) << 6);
    compute(t & 1);
  }

  // ---- epilogue: stage 32 rows x BN cols f32 in LDS per i-step, then
  // read back row-major and store full vectors (no partial lines).
  float* eps = (float*)smem;
  constexpr int REPS = (32 * BN) / (256 * 8);   // 2 for BN=128, 1 for BN=64
  float bv[REPS > 0 ? REPS : 1][8];
  if (HAS_BIAS) {
#pragma unroll
    for (int rep = 0; rep < REPS; rep++) {
      const int col = (BN == 128) ? ((tid & 15) * 8) : ((tid & 7) * 8);
      *(float4*)(bv[rep])     = *(const float4*)(bias + n0 + col);
      *(float4*)(bv[rep] + 4) = *(const float4*)(bias + n0 + col + 4);
    }
  }
#pragma unroll
  for (int i = 0; i < MI; i++) {
    __syncthreads();
#pragma unroll
    for (int j = 0; j < NJ; j++)
#pragma unroll
      for (int r = 0; r < 4; r++)
        eps[(wm * 16 + quad * 4 + r) * EW + wn * WN + j * 16 + m16] =
            acc[i][j][r];
    __syncthreads();
#pragma unroll
    for (int rep = 0; rep < REPS; rep++) {
      const int lr  = (BN == 128) ? (rep * 16 + (tid >> 4)) : (tid >> 3);
      const int col = (BN == 128) ? ((tid & 15) * 8) : ((tid & 7) * 8);
      const int rg  = m0 + (lr >> 4) * WM + i * 16 + (lr & 15);
      float v[8];
      *(float4*)(v)     = *(const float4*)(eps + lr * EW + col);
      *(float4*)(v + 4) = *(const float4*)(eps + lr * EW + col + 4);
      if (SCALE_MODE != 0) {
        float rs;
        if (SCALE_MODE == 1) rs = rowscale[rg];
        else                 rs = rsqrtf(rowscale[rg] * (1.0f / D_) + 1e-6f);
#pragma unroll
        for (int e = 0; e < 8; e++) v[e] *= rs;
      }
      if (HAS_BIAS) {
#pragma unroll
        for (int e = 0; e < 8; e++) v[e] += bv[rep][e];
      }
      if (DO_GELU) {
#pragma unroll
        for (int e = 0; e < 8; e++) v[e] = gelu_f(v[e]);
      }
      const size_t idx = (size_t)rg * N + n0 + col;
      if (RES_MODE == 1) {
        float4 r0 = *(const float4*)((const float*)resv + idx);
        float4 r1 = *(const float4*)((const float*)resv + idx + 4);
        v[0] += r0.x; v[1] += r0.y; v[2] += r0.z; v[3] += r0.w;
        v[4] += r1.x; v[5] += r1.y; v[6] += r1.z; v[7] += r1.w;
      } else if (RES_MODE == 2) {
        u16x8 rr = *(const u16x8*)((const u16*)resv + idx);
#pragma unroll
        for (int e = 0; e < 8; e++) v[e] += bf2f(rr[e]);
      }
      if (EMIT_SS) {   // per-row partial sum of squares (16 threads per row)
        float ps = 0.f;
#pragma unroll
        for (int e = 0; e < 8; e++) ps += v[e] * v[e];
        ps += __shfl_xor(ps, 1, 64);
        ps += __shfl_xor(ps, 2, 64);
        ps += __shfl_xor(ps, 4, 64);
        ps += __shfl_xor(ps, 8, 64);
        if ((tid & 15) == 0) atomicAdd(ssout + rg, ps);
      }
      if (STORE_BF16) {
        u16 o[8];
#pragma unroll
        for (int e = 0; e < 8; e++) o[e] = f2bf(v[e]);
        *(uint4*)((u16*)Cv + idx) = *(uint4*)o;
      } else {
        *(float4*)((float*)Cv + idx)     = *(float4*)(v);
        *(float4*)((float*)Cv + idx + 4) = *(float4*)(v + 4);
      }
    }
  }
}

// ---- banded attention, MFMA flash-style, full-window softmax in registers.
// LDS repack for 3 blocks/CU: Ks [208][64] with XOR chunk swizzle, Vt pitch
// 216. q-chunk index XCD-swizzled: 4 consecutive chunks per XCD so the ~75%
// overlapping K/V windows become per-XCD L2 hits.
#define VP_ 216
__global__ __launch_bounds__(256) void attn_kernel(const u16* __restrict__ qkv,
                                                   u16* __restrict__ out) {
  __shared__ __align__(16) char smem[26624 + 64 * VP_ * 2];
  u16* Ks = (u16*)smem;               // [208][64] keys, swizzled (26624 B)
  u16* Vt = (u16*)(smem + 26624);     // [64][216] V transposed (27648 B)
  const int tid = threadIdx.x, lane = tid & 63, w = tid >> 6;
  const int quad = lane >> 4, m16 = lane & 15;
  const int qc = ((blockIdx.x & 7) << 2) | (blockIdx.x >> 3);  // XCD swizzle
  const int q0 = qc * 64, h = blockIdx.y, b = blockIdx.z;
  const int kstart = q0 - 64;         // 208-key staging window
  const u16* base = qkv + (size_t)b * T_ * 1536;

  for (int c = tid; c < 1664; c += 256) {
    int row = c >> 3, ch = c & 7;
    int j = kstart + row;
    j = j < 0 ? 0 : (j > T_ - 1 ? T_ - 1 : j);   // clamp; masked later
    *(uint4*)(Ks + row * 64 + ((ch ^ (row & 7)) * 8)) =
        *(const uint4*)(base + (size_t)j * 1536 + 512 + h * 64 + ch * 8);
  }
  for (int c = tid; c < 1664; c += 256) {
    int row = c >> 3, cc = (c & 7) * 8;
    int j = kstart + row;
    j = j < 0 ? 0 : (j > T_ - 1 ? T_ - 1 : j);
    uint4 u = *(const uint4*)(base + (size_t)j * 1536 + 1024 + h * 64 + cc);
    u16 tmp[8];
    *(uint4*)tmp = u;
#pragma unroll
    for (int i = 0; i < 8; i++) Vt[(cc + i) * VP_ + row] = tmp[i];
  }
  const int qw = q0 + w * 16;
  const u16* qb = base + (size_t)(qw + m16) * 1536 + h * 64 + quad * 8;
  u16x8 a0 = *(const u16x8*)qb;
  u16x8 a1 = *(const u16x8*)(qb + 32);
  __syncthreads();

  float s[10][4];
#pragma unroll
  for (int t = 0; t < 10; t++) {
    int kt = (w + t) * 16;
    int kr = kt + m16, sw = kr & 7;
    u16x8 kb0 = *(const u16x8*)(Ks + kr * 64 + ((quad ^ sw) * 8));
    u16x8 kb1 = *(const u16x8*)(Ks + kr * 64 + (((4 + quad) ^ sw) * 8));
    f32x4 acc = {0.f, 0.f, 0.f, 0.f};
    acc = mfma_bf16(a0, kb0, acc);
    acc = mfma_bf16(a1, kb1, acc);
    int jab = kstart + kt + m16;
#pragma unroll
    for (int r = 0; r < 4; r++) {
      int q = qw + quad * 4 + r;
      int d = q - jab;
      bool valid = (jab >= 0) && (jab < T_) && (d <= 64) && (d >= -64);
      s[t][r] = valid ? acc[r] * 0.125f : -1e30f;
    }
  }
  float mx[4], sm[4];
#pragma unroll
  for (int r = 0; r < 4; r++) mx[r] = -1e30f;
#pragma unroll
  for (int t = 0; t < 10; t++)
#pragma unroll
    for (int r = 0; r < 4; r++) mx[r] = fmaxf(mx[r], s[t][r]);
#pragma unroll
  for (int r = 0; r < 4; r++) {
#pragma unroll
    for (int msk = 1; msk < 16; msk <<= 1)
      mx[r] = fmaxf(mx[r], __shfl_xor(mx[r], msk, 64));
    sm[r] = 0.f;
  }
#pragma unroll
  for (int t = 0; t < 10; t++)
#pragma unroll
    for (int r = 0; r < 4; r++) {
      float e = __expf(s[t][r] - mx[r]);
      s[t][r] = e; sm[r] += e;
    }
#pragma unroll
  for (int r = 0; r < 4; r++) {
#pragma unroll
    for (int msk = 1; msk < 16; msk <<= 1) sm[r] += __shfl_xor(sm[r], msk, 64);
    sm[r] = 1.0f / sm[r];
  }
  __syncthreads();
  u16* Ps = (u16*)smem + w * 2688;       // alias Ks region: per-wave [16][168]
#pragma unroll
  for (int t = 0; t < 10; t++)
#pragma unroll
    for (int r = 0; r < 4; r++)
      Ps[(quad * 4 + r) * 168 + t * 16 + m16] = f2bf(s[t][r] * sm[r]);
  __syncthreads();

  f32x4 o[4];
#pragma unroll
  for (int dt = 0; dt < 4; dt++) o[dt] = (f32x4){0.f, 0.f, 0.f, 0.f};
#pragma unroll
  for (int c5 = 0; c5 < 5; c5++) {
    u16x8 pa = *(const u16x8*)(Ps + m16 * 168 + c5 * 32 + quad * 8);
#pragma unroll
    for (int dt = 0; dt < 4; dt++) {
      u16x8 vb = *(const u16x8*)(Vt + (dt * 16 + m16) * VP_ + w * 16 + c5 * 32 + quad * 8);
      o[dt] = mfma_bf16(pa, vb, o[dt]);
    }
  }
#pragma unroll
  for (int dt = 0; dt < 4; dt++)
#pragma unroll
    for (int r = 0; r < 4; r++)
      out[(size_t)(b * T_ + qw + quad * 4 + r) * D_ + h * HD_ + dt * 16 + m16] =
          f2bf(o[dt][r]);
}

// ---------------------------------------------------------------------------
extern "C" void kernel_launch(void* const* d_in, const int* in_sizes, int n_in,
                              void* d_out, int out_size, void* d_ws, size_t ws_size,
                              hipStream_t stream) {
  (void)in_sizes; (void)n_in; (void)out_size; (void)ws_size;
  const float* x     = (const float*)d_in[0];
  const float* n1w   = (const float*)d_in[1];
  const float* n2w   = (const float*)d_in[2];
  const float* w_qkv = (const float*)d_in[3];
  const float* w_out = (const float*)d_in[4];
  const float* b_out = (const float*)d_in[5];
  const float* w1    = (const float*)d_in[6];
  const float* b1    = (const float*)d_in[7];
  const float* w2    = (const float*)d_in[8];
  const float* b2    = (const float*)d_in[9];
  float* out = (float*)d_out;
  char* ws = (char*)d_ws;

  // workspace layout (hbuf aliases dead qkv+attno)
  u16* wqkvT  = (u16*)(ws + 0);          // [1536][512]  1.5 MB (n1w folded)
  u16* woutT  = (u16*)(ws + 1572864);    // [512][512]   0.5 MB
  u16* w1T    = (u16*)(ws + 2097152);    // [2048][512]  2 MB  (n2w folded)
  u16* w2T    = (u16*)(ws + 4194304);    // [512][2048]  2 MB
  float* inv  = (float*)(ws + 6291456);  // [8192] f32 inv-rms of x
  float* sums = (float*)(ws + 6324224);  // [8192] f32 sumsq of x1 (atomics)
  u16* qkv    = (u16*)(ws + 14680064);   // [8192][1536] 24 MB
  u16* attno  = (u16*)(ws + 39845888);   // [8192][512]  8 MB
  u16* x1     = (u16*)(ws + 48234496);   // [8192][512]  8 MB bf16
  u16* xbf    = (u16*)(ws + 56623104);   // [8192][512]  8 MB bf16 (raw x)
  u16* hbuf   = qkv;                     // [8192][2048] 32 MB (over qkv+attno)

  // fused: weight transposes (+norm-w fold) + x->bf16 + inv-rms + ss zero
  prep_kernel<<<5152, 256, 0, stream>>>(
      w_qkv, wqkvT, w_out, woutT, w1, w1T, w2, w2T, x, n1w, n2w, inv, xbf, sums);

  // qkv = (x @ [n1w*wqkv]) * inv[row]   == rmsnorm(x,n1w) @ wqkv
  gemm_kernel<64, 128, false, 0, false, true, 1, false>
      <<<dim3(12, 128), 256, 0, stream>>>(
      xbf, wqkvT, (void*)qkv, nullptr, nullptr, inv, nullptr, M_, 3 * D_, D_);
  attn_kernel<<<dim3(32, 8, 4), 256, 0, stream>>>(qkv, attno);
  // x1 = attno @ w_out + b_out + xbf ; also emit per-row sumsq(x1) -> sums
  gemm_kernel<64, 128, true, 2, false, true, 0, true>
      <<<dim3(4, 128), 256, 0, stream>>>(
      attno, woutT, (void*)x1, b_out, xbf, nullptr, sums, M_, D_, D_);
  // hbuf = gelu( (x1 @ [n2w*w1]) * rsqrt(sums/512+eps) + b1 )  (fused rmsnorm2)
  gemm_kernel<128, 128, true, 0, true, true, 2, false>
      <<<dim3(16, 64), 256, 0, stream>>>(
      x1, w1T, (void*)hbuf, b1, nullptr, sums, nullptr, M_, FF_, D_);
  // out = hbuf @ w2 + b2 + x1   (f32 out, bf16 res)
  gemm_kernel<64, 128, true, 2, false, false, 0, false>
      <<<dim3(4, 128), 256, 0, stream>>>(
      hbuf, w2T, (void*)out, b2, x1, nullptr, nullptr, M_, D_, FF_);
}

// Round 2
// 203.450 us; speedup vs baseline: 1.0389x; 1.0231x over previous
//
#include <hip/hip_runtime.h>
#include <cstdint>
#include <cstddef>

// ---------------- problem constants (fixed by setup_inputs) ----------------
#define B_  4
#define T_  2048
#define D_  512
#define NH_ 8
#define HD_ 64
#define FF_ 2048
#define M_  (B_*T_)   // 8192 token rows

typedef unsigned short u16;
typedef __attribute__((ext_vector_type(8))) unsigned short u16x8;
typedef __attribute__((ext_vector_type(8))) __bf16         bf16x8;
typedef __attribute__((ext_vector_type(4))) float          f32x4;

__device__ __forceinline__ u16 f2bf(float f) {            // RNE f32 -> bf16
  unsigned u = __float_as_uint(f);
  u += 0x7FFF + ((u >> 16) & 1);
  return (u16)(u >> 16);
}
__device__ __forceinline__ float bf2f(u16 h) {
  return __uint_as_float((unsigned)h << 16);
}

__device__ __forceinline__ f32x4 mfma_bf16(u16x8 a, u16x8 b, f32x4 c) {
  return __builtin_amdgcn_mfma_f32_16x16x32_bf16(
      __builtin_bit_cast(bf16x8, a), __builtin_bit_cast(bf16x8, b), c, 0, 0, 0);
}

// async global->LDS, 16B per lane; LDS dest = wave-uniform base + lane*16
__device__ __forceinline__ void async16(const void* g, void* l) {
  __builtin_amdgcn_global_load_lds(
      (const __attribute__((address_space(1))) unsigned int*)g,
      (__attribute__((address_space(3))) unsigned int*)l, 16, 0, 0);
}

// Branchless GELU via A&S 7.1.26 erf (|err| <= 1.5e-7).
__device__ __forceinline__ float gelu_f(float v) {
  float ax = fabsf(v) * 0.70710678118f;
  float t = 1.0f / (1.0f + 0.3275911f * ax);
  float p = ((((1.061405429f * t - 1.453152027f) * t + 1.421413741f) * t
              - 0.284496736f) * t + 0.254829592f) * t;
  float e = __expf(-ax * ax);
  float er = 1.0f - p * e;
  float s = (v >= 0.0f) ? er : -er;
  return 0.5f * v * (1.0f + s);
}

// ---- fused prep: 4 weight transposes (norm weights FOLDED into wqkv/w1)
// + x->bf16 + per-row inv-rms + sumsq zeroing, in ONE launch.
// blocks 0..3071: transpose tiles; 3072..5119: row pass; 5120..5151: zero ss.
__global__ __launch_bounds__(256) void prep_kernel(
    const float* __restrict__ i0, u16* __restrict__ o0,   // wqkv 512x1536
    const float* __restrict__ i1, u16* __restrict__ o1,   // wout 512x512
    const float* __restrict__ i2, u16* __restrict__ o2,   // w1   512x2048
    const float* __restrict__ i3, u16* __restrict__ o3,   // w2   2048x512
    const float* __restrict__ x, const float* __restrict__ n1w,
    const float* __restrict__ n2w,
    float* __restrict__ inv, u16* __restrict__ xbf, float* __restrict__ ssz) {
  __shared__ float tile[32][33];
  const int bid = blockIdx.x, tid = threadIdx.x;
  if (bid < 3072) {
    const float* in; u16* out; const float* sc; int R, C, gx, lb;
    if (bid < 768)       { in = i0; out = o0; R = 512;  C = 1536; gx = 48; lb = bid;        sc = n1w; }
    else if (bid < 1024) { in = i1; out = o1; R = 512;  C = 512;  gx = 16; lb = bid - 768;  sc = nullptr; }
    else if (bid < 2048) { in = i2; out = o2; R = 512;  C = 2048; gx = 64; lb = bid - 1024; sc = n2w; }
    else                 { in = i3; out = o3; R = 2048; C = 512;  gx = 16; lb = bid - 2048; sc = nullptr; }
    int c0 = (lb % gx) * 32, r0 = (lb / gx) * 32;
    int tx = tid & 31, ty = tid >> 5;  // 32x8
#pragma unroll
    for (int i = 0; i < 4; i++)
      tile[ty + i * 8][tx] = in[(size_t)(r0 + ty + i * 8) * C + c0 + tx];
    __syncthreads();
    float s = sc ? sc[r0 + tx] : 1.0f;   // k-index = r0+tx after transpose
#pragma unroll
    for (int i = 0; i < 4; i++)
      out[(size_t)(c0 + ty + i * 8) * R + r0 + tx] = f2bf(tile[tx][ty + i * 8] * s);
  } else if (bid < 5120) {
    int row  = (bid - 3072) * 4 + (tid >> 6);
    int lane = tid & 63;
    const float* xr = x + (size_t)row * D_ + lane * 8;
    float v[8];
    *(float4*)(v)     = *(const float4*)xr;
    *(float4*)(v + 4) = *(const float4*)(xr + 4);
    u16 rw[8];
#pragma unroll
    for (int e = 0; e < 8; e++) rw[e] = f2bf(v[e]);
    *(uint4*)(xbf + (size_t)row * D_ + lane * 8) = *(uint4*)rw;
    float ss = 0.f;
#pragma unroll
    for (int e = 0; e < 8; e++) ss += v[e] * v[e];
#pragma unroll
    for (int m = 1; m < 64; m <<= 1) ss += __shfl_xor(ss, m, 64);
    if (lane == 0) inv[row] = rsqrtf(ss * (1.0f / D_) + 1e-6f);
  } else {
    ssz[(bid - 5120) * 256 + tid] = 0.f;   // 32*256 = 8192 rows
  }
}

// ---- bf16 MFMA GEMM: C[M,N] = A[M,K] * Bt[N,K]^T (+rowscale)(+bias)(gelu)(+res)
// BM x BN tile, BK=64, double-buffered LDS, prefetch-after-barrier.
// XOR-swizzled LDS: 16B chunk c (of 8) of row r at physical slot c^(r&7).
// RES_MODE: 0 none, 1 f32, 2 bf16.
// SCALE_MODE (applied to acc BEFORE bias): 0 none, 1 v*=rowscale[rg],
//   2 v*=rsqrt(rowscale[rg]/512+eps)  (fused rmsnorm; norm weight folded in Bt).
// EMIT_SS: per-row partial sum of squares of FINAL value -> atomicAdd(ssout).
// 1D grid with XCD working-set swizzle: wg->xcd = wg&7 (round-robin, m09);
// each XCD owns a contiguous 1/8 of the m-panels x ALL n-panels, consecutive
// slots sweep n for a fixed m-panel. Per-XCD working set (A-chunk + full B)
// fits the 4MB per-XCD L2, so staging re-reads come from L2 not L3.
template <int BM, int BN, bool HAS_BIAS, int RES_MODE, bool DO_GELU,
          bool STORE_BF16, int SCALE_MODE, bool EMIT_SS>
__global__ __launch_bounds__(256) void gemm_kernel(
    const u16* __restrict__ A, const u16* __restrict__ Bt, void* __restrict__ Cv,
    const float* __restrict__ bias, const void* __restrict__ resv,
    const float* __restrict__ rowscale, float* __restrict__ ssout,
    int M, int N, int K) {
  constexpr int ACH = BM / 32;              // A staging chunks (32 rows each)
  constexpr int BCH = BN / 32;              // B staging chunks
  constexpr int WM  = BM / 2, WN = BN / 2;  // per-wave tile
  constexpr int MI  = WM / 16, NJ = WN / 16;
  constexpr int EW  = BN + 4;               // epilogue LDS row pitch (f32)
  constexpr int STG = (BM + BN) * 128;      // bytes per stage buffer (A+B)
  constexpr int EPB = 32 * EW * 4;          // epilogue bytes
  constexpr int SMB = (2 * STG > EPB) ? 2 * STG : EPB;
  __shared__ __align__(16) char smem[SMB];
  const int tid = threadIdx.x;
  const int lane = tid & 63, w = tid >> 6;
  const int quad = lane >> 4, m16 = lane & 15;
  const int wm = w & 1, wn = w >> 1;

  // XCD working-set swizzle (bijective; requires (M/BM)%8==0, true for all uses)
  const int nbx  = N / BN;
  const int wg   = blockIdx.x;
  const int xcd  = wg & 7, slot = wg >> 3;
  const int mper = (M / BM) >> 3;           // m-panels per XCD
  const int mloc = slot / nbx;
  const int nxp  = slot - mloc * nbx;
  const int m0 = (xcd * mper + mloc) * BM, n0 = nxp * BN;

  f32x4 acc[MI][NJ];
#pragma unroll
  for (int i = 0; i < MI; i++)
#pragma unroll
    for (int j = 0; j < NJ; j++) acc[i][j] = (f32x4){0.f, 0.f, 0.f, 0.f};

  const int srow = tid >> 3;                       // 0..31
  const int scol = (((tid & 7) ^ (srow & 7))) * 8; // swizzled source k-chunk
  const u16* Ag = A  + (size_t)(m0 + srow) * K + scol;
  const u16* Bg = Bt + (size_t)(n0 + srow) * K + scol;

  auto stage = [&](int buf, int kt) {
    char* base = smem + buf * STG;
#pragma unroll
    for (int c = 0; c < ACH; c++)
      async16(Ag + (size_t)c * 32 * K + kt, base + c * 4096 + tid * 16);
#pragma unroll
    for (int c = 0; c < BCH; c++)
      async16(Bg + (size_t)c * 32 * K + kt, base + BM * 128 + c * 4096 + tid * 16);
  };
  auto compute = [&](int buf) {
    const u16* lA = (const u16*)(smem + buf * STG);
    const u16* lB = (const u16*)(smem + buf * STG + BM * 128);
#pragma unroll
    for (int kk = 0; kk < 2; kk++) {
      const int sl = ((kk * 4 + quad) ^ (m16 & 7)) * 8;  // physical slot
      const u16* pa = lA + (wm * WM + m16) * 64 + sl;
      const u16* pb = lB + (wn * WN + m16) * 64 + sl;
      u16x8 af[MI], bfr[NJ];
#pragma unroll
      for (int i = 0; i < MI; i++) af[i] = *(const u16x8*)(pa + i * 1024);
#pragma unroll
      for (int j = 0; j < NJ; j++) bfr[j] = *(const u16x8*)(pb + j * 1024);
#pragma unroll
      for (int i = 0; i < MI; i++)
#pragma unroll
        for (int j = 0; j < NJ; j++)
          acc[i][j] = mfma_bf16(af[i], bfr[j], acc[i][j]);
    }
  };

  const int nk = K >> 6;
  stage(0, 0);
  for (int t = 0; t < nk; t++) {
    __syncthreads();                // drains stage(t); covered by compute(t-1)
    if (t + 1 < nk) stage((t + 1) & 1, (t + 1) << 6);
    compute(t & 1);
  }

  // ---- epilogue: stage 32 rows x BN cols f32 in LDS per i-step, then
  // read back row-major and store full vectors (no partial lines).
  float* eps = (float*)smem;
  constexpr int REPS = (32 * BN) / (256 * 8);   // 2 for BN=128, 1 for BN=64
  float bv[REPS > 0 ? REPS : 1][8];
  if (HAS_BIAS) {
#pragma unroll
    for (int rep = 0; rep < REPS; rep++) {
      const int col = (BN == 128) ? ((tid & 15) * 8) : ((tid & 7) * 8);
      *(float4*)(bv[rep])     = *(const float4*)(bias + n0 + col);
      *(float4*)(bv[rep] + 4) = *(const float4*)(bias + n0 + col + 4);
    }
  }
#pragma unroll
  for (int i = 0; i < MI; i++) {
    __syncthreads();
#pragma unroll
    for (int j = 0; j < NJ; j++)
#pragma unroll
      for (int r = 0; r < 4; r++)
        eps[(wm * 16 + quad * 4 + r) * EW + wn * WN + j * 16 + m16] =
            acc[i][j][r];
    __syncthreads();
#pragma unroll
    for (int rep = 0; rep < REPS; rep++) {
      const int lr  = (BN == 128) ? (rep * 16 + (tid >> 4)) : (tid >> 3);
      const int col = (BN == 128) ? ((tid & 15) * 8) : ((tid & 7) * 8);
      const int rg  = m0 + (lr >> 4) * WM + i * 16 + (lr & 15);
      float v[8];
      *(float4*)(v)     = *(const float4*)(eps + lr * EW + col);
      *(float4*)(v + 4) = *(const float4*)(eps + lr * EW + col + 4);
      if (SCALE_MODE != 0) {
        float rs;
        if (SCALE_MODE == 1) rs = rowscale[rg];
        else                 rs = rsqrtf(rowscale[rg] * (1.0f / D_) + 1e-6f);
#pragma unroll
        for (int e = 0; e < 8; e++) v[e] *= rs;
      }
      if (HAS_BIAS) {
#pragma unroll
        for (int e = 0; e < 8; e++) v[e] += bv[rep][e];
      }
      if (DO_GELU) {
#pragma unroll
        for (int e = 0; e < 8; e++) v[e] = gelu_f(v[e]);
      }
      const size_t idx = (size_t)rg * N + n0 + col;
      if (RES_MODE == 1) {
        float4 r0 = *(const float4*)((const float*)resv + idx);
        float4 r1 = *(const float4*)((const float*)resv + idx + 4);
        v[0] += r0.x; v[1] += r0.y; v[2] += r0.z; v[3] += r0.w;
        v[4] += r1.x; v[5] += r1.y; v[6] += r1.z; v[7] += r1.w;
      } else if (RES_MODE == 2) {
        u16x8 rr = *(const u16x8*)((const u16*)resv + idx);
#pragma unroll
        for (int e = 0; e < 8; e++) v[e] += bf2f(rr[e]);
      }
      if (EMIT_SS) {   // per-row partial sum of squares (16 threads per row)
        float ps = 0.f;
#pragma unroll
        for (int e = 0; e < 8; e++) ps += v[e] * v[e];
        ps += __shfl_xor(ps, 1, 64);
        ps += __shfl_xor(ps, 2, 64);
        ps += __shfl_xor(ps, 4, 64);
        ps += __shfl_xor(ps, 8, 64);
        if ((tid & 15) == 0) atomicAdd(ssout + rg, ps);
      }
      if (STORE_BF16) {
        u16 o[8];
#pragma unroll
        for (int e = 0; e < 8; e++) o[e] = f2bf(v[e]);
        *(uint4*)((u16*)Cv + idx) = *(uint4*)o;
      } else {
        *(float4*)((float*)Cv + idx)     = *(float4*)(v);
        *(float4*)((float*)Cv + idx + 4) = *(float4*)(v + 4);
      }
    }
  }
}

// ---- banded attention, MFMA flash-style, full-window softmax in registers.
// LDS repack for 3 blocks/CU: Ks [208][64] with XOR chunk swizzle, Vt pitch
// 216. q-chunk index XCD-swizzled: 4 consecutive chunks per XCD so the ~75%
// overlapping K/V windows become per-XCD L2 hits.
#define VP_ 216
__global__ __launch_bounds__(256) void attn_kernel(const u16* __restrict__ qkv,
                                                   u16* __restrict__ out) {
  __shared__ __align__(16) char smem[26624 + 64 * VP_ * 2];
  u16* Ks = (u16*)smem;               // [208][64] keys, swizzled (26624 B)
  u16* Vt = (u16*)(smem + 26624);     // [64][216] V transposed (27648 B)
  const int tid = threadIdx.x, lane = tid & 63, w = tid >> 6;
  const int quad = lane >> 4, m16 = lane & 15;
  const int qc = ((blockIdx.x & 7) << 2) | (blockIdx.x >> 3);  // XCD swizzle
  const int q0 = qc * 64, h = blockIdx.y, b = blockIdx.z;
  const int kstart = q0 - 64;         // 208-key staging window
  const u16* base = qkv + (size_t)b * T_ * 1536;

  for (int c = tid; c < 1664; c += 256) {
    int row = c >> 3, ch = c & 7;
    int j = kstart + row;
    j = j < 0 ? 0 : (j > T_ - 1 ? T_ - 1 : j);   // clamp; masked later
    *(uint4*)(Ks + row * 64 + ((ch ^ (row & 7)) * 8)) =
        *(const uint4*)(base + (size_t)j * 1536 + 512 + h * 64 + ch * 8);
  }
  for (int c = tid; c < 1664; c += 256) {
    int row = c >> 3, cc = (c & 7) * 8;
    int j = kstart + row;
    j = j < 0 ? 0 : (j > T_ - 1 ? T_ - 1 : j);
    uint4 u = *(const uint4*)(base + (size_t)j * 1536 + 1024 + h * 64 + cc);
    u16 tmp[8];
    *(uint4*)tmp = u;
#pragma unroll
    for (int i = 0; i < 8; i++) Vt[(cc + i) * VP_ + row] = tmp[i];
  }
  const int qw = q0 + w * 16;
  const u16* qb = base + (size_t)(qw + m16) * 1536 + h * 64 + quad * 8;
  u16x8 a0 = *(const u16x8*)qb;
  u16x8 a1 = *(const u16x8*)(qb + 32);
  __syncthreads();

  float s[10][4];
#pragma unroll
  for (int t = 0; t < 10; t++) {
    int kt = (w + t) * 16;
    int kr = kt + m16, sw = kr & 7;
    u16x8 kb0 = *(const u16x8*)(Ks + kr * 64 + ((quad ^ sw) * 8));
    u16x8 kb1 = *(const u16x8*)(Ks + kr * 64 + (((4 + quad) ^ sw) * 8));
    f32x4 acc = {0.f, 0.f, 0.f, 0.f};
    acc = mfma_bf16(a0, kb0, acc);
    acc = mfma_bf16(a1, kb1, acc);
    int jab = kstart + kt + m16;
#pragma unroll
    for (int r = 0; r < 4; r++) {
      int q = qw + quad * 4 + r;
      int d = q - jab;
      bool valid = (jab >= 0) && (jab < T_) && (d <= 64) && (d >= -64);
      s[t][r] = valid ? acc[r] * 0.125f : -1e30f;
    }
  }
  float mx[4], sm[4];
#pragma unroll
  for (int r = 0; r < 4; r++) mx[r] = -1e30f;
#pragma unroll
  for (int t = 0; t < 10; t++)
#pragma unroll
    for (int r = 0; r < 4; r++) mx[r] = fmaxf(mx[r], s[t][r]);
#pragma unroll
  for (int r = 0; r < 4; r++) {
#pragma unroll
    for (int msk = 1; msk < 16; msk <<= 1)
      mx[r] = fmaxf(mx[r], __shfl_xor(mx[r], msk, 64));
    sm[r] = 0.f;
  }
#pragma unroll
  for (int t = 0; t < 10; t++)
#pragma unroll
    for (int r = 0; r < 4; r++) {
      float e = __expf(s[t][r] - mx[r]);
      s[t][r] = e; sm[r] += e;
    }
#pragma unroll
  for (int r = 0; r < 4; r++) {
#pragma unroll
    for (int msk = 1; msk < 16; msk <<= 1) sm[r] += __shfl_xor(sm[r], msk, 64);
    sm[r] = 1.0f / sm[r];
  }
  __syncthreads();
  u16* Ps = (u16*)smem + w * 2688;       // alias Ks region: per-wave [16][168]
#pragma unroll
  for (int t = 0; t < 10; t++)
#pragma unroll
    for (int r = 0; r < 4; r++)
      Ps[(quad * 4 + r) * 168 + t * 16 + m16] = f2bf(s[t][r] * sm[r]);
  __syncthreads();

  f32x4 o[4];
#pragma unroll
  for (int dt = 0; dt < 4; dt++) o[dt] = (f32x4){0.f, 0.f, 0.f, 0.f};
#pragma unroll
  for (int c5 = 0; c5 < 5; c5++) {
    u16x8 pa = *(const u16x8*)(Ps + m16 * 168 + c5 * 32 + quad * 8);
#pragma unroll
    for (int dt = 0; dt < 4; dt++) {
      u16x8 vb = *(const u16x8*)(Vt + (dt * 16 + m16) * VP_ + w * 16 + c5 * 32 + quad * 8);
      o[dt] = mfma_bf16(pa, vb, o[dt]);
    }
  }
#pragma unroll
  for (int dt = 0; dt < 4; dt++)
#pragma unroll
    for (int r = 0; r < 4; r++)
      out[(size_t)(b * T_ + qw + quad * 4 + r) * D_ + h * HD_ + dt * 16 + m16] =
          f2bf(o[dt][r]);
}

// ---------------------------------------------------------------------------
extern "C" void kernel_launch(void* const* d_in, const int* in_sizes, int n_in,
                              void* d_out, int out_size, void* d_ws, size_t ws_size,
                              hipStream_t stream) {
  (void)in_sizes; (void)n_in; (void)out_size; (void)ws_size;
  const float* x     = (const float*)d_in[0];
  const float* n1w   = (const float*)d_in[1];
  const float* n2w   = (const float*)d_in[2];
  const float* w_qkv = (const float*)d_in[3];
  const float* w_out = (const float*)d_in[4];
  const float* b_out = (const float*)d_in[5];
  const float* w1    = (const float*)d_in[6];
  const float* b1    = (const float*)d_in[7];
  const float* w2    = (const float*)d_in[8];
  const float* b2    = (const float*)d_in[9];
  float* out = (float*)d_out;
  char* ws = (char*)d_ws;

  // workspace layout (hbuf aliases dead qkv+attno)
  u16* wqkvT  = (u16*)(ws + 0);          // [1536][512]  1.5 MB (n1w folded)
  u16* woutT  = (u16*)(ws + 1572864);    // [512][512]   0.5 MB
  u16* w1T    = (u16*)(ws + 2097152);    // [2048][512]  2 MB  (n2w folded)
  u16* w2T    = (u16*)(ws + 4194304);    // [512][2048]  2 MB
  float* inv  = (float*)(ws + 6291456);  // [8192] f32 inv-rms of x
  float* sums = (float*)(ws + 6324224);  // [8192] f32 sumsq of x1 (atomics)
  u16* qkv    = (u16*)(ws + 14680064);   // [8192][1536] 24 MB
  u16* attno  = (u16*)(ws + 39845888);   // [8192][512]  8 MB
  u16* x1     = (u16*)(ws + 48234496);   // [8192][512]  8 MB bf16
  u16* xbf    = (u16*)(ws + 56623104);   // [8192][512]  8 MB bf16 (raw x)
  u16* hbuf   = qkv;                     // [8192][2048] 32 MB (over qkv+attno)

  // fused: weight transposes (+norm-w fold) + x->bf16 + inv-rms + ss zero
  prep_kernel<<<5152, 256, 0, stream>>>(
      w_qkv, wqkvT, w_out, woutT, w1, w1T, w2, w2T, x, n1w, n2w, inv, xbf, sums);

  // qkv = (x @ [n1w*wqkv]) * inv[row]   == rmsnorm(x,n1w) @ wqkv
  gemm_kernel<64, 128, false, 0, false, true, 1, false>
      <<<dim3(12 * 128), 256, 0, stream>>>(
      xbf, wqkvT, (void*)qkv, nullptr, nullptr, inv, nullptr, M_, 3 * D_, D_);
  attn_kernel<<<dim3(32, 8, 4), 256, 0, stream>>>(qkv, attno);
  // x1 = attno @ w_out + b_out + xbf ; also emit per-row sumsq(x1) -> sums
  gemm_kernel<64, 128, true, 2, false, true, 0, true>
      <<<dim3(4 * 128), 256, 0, stream>>>(
      attno, woutT, (void*)x1, b_out, xbf, nullptr, sums, M_, D_, D_);
  // hbuf = gelu( (x1 @ [n2w*w1]) * rsqrt(sums/512+eps) + b1 )  (fused rmsnorm2)
  gemm_kernel<128, 128, true, 0, true, true, 2, false>
      <<<dim3(16 * 64), 256, 0, stream>>>(
      x1, w1T, (void*)hbuf, b1, nullptr, sums, nullptr, M_, FF_, D_);
  // out = hbuf @ w2 + b2 + x1   (f32 out, bf16 res)
  gemm_kernel<64, 128, true, 2, false, false, 0, false>
      <<<dim3(4 * 128), 256, 0, stream>>>(
      hbuf, w2T, (void*)out, b2, x1, nullptr, nullptr, M_, D_, FF_);
}

// Round 3
// 202.573 us; speedup vs baseline: 1.0434x; 1.0043x over previous
//
#include <hip/hip_runtime.h>
#include <cstdint>
#include <cstddef>

// ---------------- problem constants (fixed by setup_inputs) ----------------
#define B_  4
#define T_  2048
#define D_  512
#define NH_ 8
#define HD_ 64
#define FF_ 2048
#define M_  (B_*T_)   // 8192 token rows

typedef unsigned short u16;
typedef __attribute__((ext_vector_type(8))) unsigned short u16x8;
typedef __attribute__((ext_vector_type(8))) __bf16         bf16x8;
typedef __attribute__((ext_vector_type(4))) float          f32x4;

__device__ __forceinline__ u16 f2bf(float f) {            // RNE f32 -> bf16
  unsigned u = __float_as_uint(f);
  u += 0x7FFF + ((u >> 16) & 1);
  return (u16)(u >> 16);
}
__device__ __forceinline__ float bf2f(u16 h) {
  return __uint_as_float((unsigned)h << 16);
}

__device__ __forceinline__ f32x4 mfma_bf16(u16x8 a, u16x8 b, f32x4 c) {
  return __builtin_amdgcn_mfma_f32_16x16x32_bf16(
      __builtin_bit_cast(bf16x8, a), __builtin_bit_cast(bf16x8, b), c, 0, 0, 0);
}

// async global->LDS, 16B per lane; LDS dest = wave-uniform base + lane*16
__device__ __forceinline__ void async16(const void* g, void* l) {
  __builtin_amdgcn_global_load_lds(
      (const __attribute__((address_space(1))) unsigned int*)g,
      (__attribute__((address_space(3))) unsigned int*)l, 16, 0, 0);
}

// Branchless GELU via A&S 7.1.26 erf (|err| <= 1.5e-7).
__device__ __forceinline__ float gelu_f(float v) {
  float ax = fabsf(v) * 0.70710678118f;
  float t = 1.0f / (1.0f + 0.3275911f * ax);
  float p = ((((1.061405429f * t - 1.453152027f) * t + 1.421413741f) * t
              - 0.284496736f) * t + 0.254829592f) * t;
  float e = __expf(-ax * ax);
  float er = 1.0f - p * e;
  float s = (v >= 0.0f) ? er : -er;
  return 0.5f * v * (1.0f + s);
}

// ---- fused prep: 4 weight transposes (norm weights FOLDED into wqkv/w1)
// + x->bf16 + per-row inv-rms + sumsq zeroing, in ONE launch.
__global__ __launch_bounds__(256) void prep_kernel(
    const float* __restrict__ i0, u16* __restrict__ o0,   // wqkv 512x1536
    const float* __restrict__ i1, u16* __restrict__ o1,   // wout 512x512
    const float* __restrict__ i2, u16* __restrict__ o2,   // w1   512x2048
    const float* __restrict__ i3, u16* __restrict__ o3,   // w2   2048x512
    const float* __restrict__ x, const float* __restrict__ n1w,
    const float* __restrict__ n2w,
    float* __restrict__ inv, u16* __restrict__ xbf, float* __restrict__ ssz) {
  __shared__ float tile[32][33];
  const int bid = blockIdx.x, tid = threadIdx.x;
  if (bid < 3072) {
    const float* in; u16* out; const float* sc; int R, C, gx, lb;
    if (bid < 768)       { in = i0; out = o0; R = 512;  C = 1536; gx = 48; lb = bid;        sc = n1w; }
    else if (bid < 1024) { in = i1; out = o1; R = 512;  C = 512;  gx = 16; lb = bid - 768;  sc = nullptr; }
    else if (bid < 2048) { in = i2; out = o2; R = 512;  C = 2048; gx = 64; lb = bid - 1024; sc = n2w; }
    else                 { in = i3; out = o3; R = 2048; C = 512;  gx = 16; lb = bid - 2048; sc = nullptr; }
    int c0 = (lb % gx) * 32, r0 = (lb / gx) * 32;
    int tx = tid & 31, ty = tid >> 5;  // 32x8
#pragma unroll
    for (int i = 0; i < 4; i++)
      tile[ty + i * 8][tx] = in[(size_t)(r0 + ty + i * 8) * C + c0 + tx];
    __syncthreads();
    float s = sc ? sc[r0 + tx] : 1.0f;   // k-index = r0+tx after transpose
#pragma unroll
    for (int i = 0; i < 4; i++)
      out[(size_t)(c0 + ty + i * 8) * R + r0 + tx] = f2bf(tile[tx][ty + i * 8] * s);
  } else if (bid < 5120) {
    int row  = (bid - 3072) * 4 + (tid >> 6);
    int lane = tid & 63;
    const float* xr = x + (size_t)row * D_ + lane * 8;
    float v[8];
    *(float4*)(v)     = *(const float4*)xr;
    *(float4*)(v + 4) = *(const float4*)(xr + 4);
    u16 rw[8];
#pragma unroll
    for (int e = 0; e < 8; e++) rw[e] = f2bf(v[e]);
    *(uint4*)(xbf + (size_t)row * D_ + lane * 8) = *(uint4*)rw;
    float ss = 0.f;
#pragma unroll
    for (int e = 0; e < 8; e++) ss += v[e] * v[e];
#pragma unroll
    for (int m = 1; m < 64; m <<= 1) ss += __shfl_xor(ss, m, 64);
    if (lane == 0) inv[row] = rsqrtf(ss * (1.0f / D_) + 1e-6f);
  } else {
    ssz[(bid - 5120) * 256 + tid] = 0.f;   // 32*256 = 8192 rows
  }
}

// ---- 8-phase 256x256 bf16 MFMA GEMM (T3+T4+T5), 512 threads (2Mx4N waves),
// BK=64, 128 KB LDS: A0|A1|B0|B1 (32 KB each; buf0 even K-tiles, buf1 odd).
// Per K-tile: 4 phases = output-row strips (32 rows/wave each); B-frags load
// once into regs at phase 0 (B halves then dead -> restageable ph1+); A halves
// dead after ph3 (restageable ph4+). One half-tile (2 global_load_lds/thread)
// staged per phase. Counted vmcnt(4) ONCE per K-tile, placed BEFORE the
// phase-3/7 trailing barrier (barrier globalizes per-wave completion);
// vmcnt(0) only at final drain. setprio(1) around MFMA clusters.
// Staging: pre-swizzled global source + linear LDS dest (conflict-free reads).
template <bool HAS_BIAS, int SCALE_MODE, bool DO_GELU>
__global__ __launch_bounds__(512) void gemm256_kernel(
    const u16* __restrict__ A, const u16* __restrict__ Bt, u16* __restrict__ C,
    const float* __restrict__ bias, const float* __restrict__ rowscale,
    int M, int N, int K) {
  extern __shared__ __align__(16) char dsmem[];
  const int tid = threadIdx.x;
  const int lane = tid & 63, w = tid >> 6;
  const int quad = lane >> 4, m16 = lane & 15;
  const int wm = w & 1, wn = w >> 1;         // 2 x 4 wave grid
  // XCD working-set swizzle (bijective; (M/256)%8==0 for all uses)
  const int nbx = N >> 8;
  const int wg  = blockIdx.x;
  const int xcd = wg & 7, slot = wg >> 3;
  const int mper = (M >> 8) >> 3;
  const int mloc = slot / nbx, nxp = slot - mloc * nbx;
  const int m0 = (xcd * mper + mloc) << 8, n0 = nxp << 8;

  const int srow = tid >> 3;                        // 0..63
  const int scol = ((tid & 7) ^ (srow & 7)) * 8;    // swizzled source k-chunk
  const u16* Ag = A  + (size_t)(m0 + srow) * K + scol;
  const u16* Bg = Bt + (size_t)(n0 + srow) * K + scol;

  auto stA = [&](int bsel, int kt, int half) {      // one 128-row half of A
    char* d = dsmem + bsel * 32768 + half * 16384 + tid * 16;
#pragma unroll
    for (int c = 0; c < 2; c++)
      async16(Ag + (size_t)(half * 128 + c * 64) * K + kt * 64, d + c * 8192);
  };
  auto stB = [&](int bsel, int kt, int half) {
    char* d = dsmem + 65536 + bsel * 32768 + half * 16384 + tid * 16;
#pragma unroll
    for (int c = 0; c < 2; c++)
      async16(Bg + (size_t)(half * 128 + c * 64) * K + kt * 64, d + c * 8192);
  };

  f32x4 acc[8][4];
#pragma unroll
  for (int i = 0; i < 8; i++)
#pragma unroll
    for (int j = 0; j < 4; j++) acc[i][j] = (f32x4){0.f, 0.f, 0.f, 0.f};

  const int nk = K >> 6, nt = nk >> 1;
  // prologue: tiles 0 (buf0) and 1 (buf1), then certify tile0 (+barrier)
  stA(0, 0, 0); stA(0, 0, 1); stB(0, 0, 0); stB(0, 0, 1);
  stA(1, 1, 0); stA(1, 1, 1); stB(1, 1, 0); stB(1, 1, 1);
  asm volatile("s_waitcnt vmcnt(8)" ::: "memory");
  __builtin_amdgcn_s_barrier();

  const u16* lA0 = (const u16*)(dsmem);
  const u16* lA1 = (const u16*)(dsmem + 32768);
  const u16* lB0 = (const u16*)(dsmem + 65536);
  const u16* lB1 = (const u16*)(dsmem + 98304);

  for (int t = 0; t < nt; ++t) {
    const int t2 = t << 1;
    const bool last = (t == nt - 1);
    u16x8 bfr[4][2];
    // ---------- phases 0..3 : K-tile t2 (buf0) ----------
#pragma unroll
    for (int q = 0; q < 4; ++q) {
      if (q == 0) {
#pragma unroll
        for (int j = 0; j < 4; ++j)
#pragma unroll
          for (int kk = 0; kk < 2; ++kk)
            bfr[j][kk] = *(const u16x8*)(lB0 + (wn * 64 + j * 16 + m16) * 64 +
                                         (((kk * 4 + quad) ^ (m16 & 7)) * 8));
      }
      u16x8 af[2][2];
#pragma unroll
      for (int s = 0; s < 2; ++s)
#pragma unroll
        for (int kk = 0; kk < 2; ++kk)
          af[s][kk] = *(const u16x8*)(lA0 + (wm * 128 + (q * 2 + s) * 16 + m16) * 64 +
                                      (((kk * 4 + quad) ^ (m16 & 7)) * 8));
      if (q == 0 && t >= 1) stA(1, t2 + 1, 0);
      if (q == 1) {
        if (t >= 1) stA(1, t2 + 1, 1);
        if (t2 + 2 < nk) stB(0, t2 + 2, 0);
      }
      if (q == 2 && t2 + 2 < nk) stB(0, t2 + 2, 1);
      __builtin_amdgcn_s_barrier();
      asm volatile("s_waitcnt lgkmcnt(0)" ::: "memory");
      __builtin_amdgcn_s_setprio(1);
#pragma unroll
      for (int s = 0; s < 2; ++s)
#pragma unroll
        for (int kk = 0; kk < 2; ++kk)
#pragma unroll
          for (int j = 0; j < 4; ++j)
            acc[q * 2 + s][j] = mfma_bf16(af[s][kk], bfr[j][kk], acc[q * 2 + s][j]);
      __builtin_amdgcn_s_setprio(0);
      if (q == 3) {                 // certify buf1 K-tile t2+1 before ph4 reads
        if (last) asm volatile("s_waitcnt vmcnt(0)" ::: "memory");
        else      asm volatile("s_waitcnt vmcnt(4)" ::: "memory");
      }
      __builtin_amdgcn_s_barrier();
    }
    // ---------- phases 4..7 : K-tile t2+1 (buf1) ----------
#pragma unroll
    for (int q = 0; q < 4; ++q) {
      if (q == 0) {
#pragma unroll
        for (int j = 0; j < 4; ++j)
#pragma unroll
          for (int kk = 0; kk < 2; ++kk)
            bfr[j][kk] = *(const u16x8*)(lB1 + (wn * 64 + j * 16 + m16) * 64 +
                                         (((kk * 4 + quad) ^ (m16 & 7)) * 8));
      }
      u16x8 af[2][2];
#pragma unroll
      for (int s = 0; s < 2; ++s)
#pragma unroll
        for (int kk = 0; kk < 2; ++kk)
          af[s][kk] = *(const u16x8*)(lA1 + (wm * 128 + (q * 2 + s) * 16 + m16) * 64 +
                                      (((kk * 4 + quad) ^ (m16 & 7)) * 8));
      if (q == 0 && t2 + 2 < nk) stA(0, t2 + 2, 0);
      if (q == 1) {
        if (t2 + 2 < nk) stA(0, t2 + 2, 1);
        if (t2 + 3 < nk) stB(1, t2 + 3, 0);
      }
      if (q == 2 && t2 + 3 < nk) stB(1, t2 + 3, 1);
      __builtin_amdgcn_s_barrier();
      asm volatile("s_waitcnt lgkmcnt(0)" ::: "memory");
      __builtin_amdgcn_s_setprio(1);
#pragma unroll
      for (int s = 0; s < 2; ++s)
#pragma unroll
        for (int kk = 0; kk < 2; ++kk)
#pragma unroll
          for (int j = 0; j < 4; ++j)
            acc[q * 2 + s][j] = mfma_bf16(af[s][kk], bfr[j][kk], acc[q * 2 + s][j]);
      __builtin_amdgcn_s_setprio(0);
      if (q == 3 && !last)          // certify buf0 K-tile t2+2 before next iter
        asm volatile("s_waitcnt vmcnt(4)" ::: "memory");
      __builtin_amdgcn_s_barrier();
    }
  }

  // ---- epilogue: per i-step stage 32 rows x 256 cols f32 in LDS (pitch 260),
  // read back row-major, apply scale/bias/gelu, store bf16.
  __syncthreads();
  float* eps = (float*)dsmem;
  const int ecol = (tid & 31) * 8;
  float bv[8];
  if (HAS_BIAS) {
    *(float4*)(bv)     = *(const float4*)(bias + n0 + ecol);
    *(float4*)(bv + 4) = *(const float4*)(bias + n0 + ecol + 4);
  }
#pragma unroll
  for (int i = 0; i < 8; ++i) {
    __syncthreads();
#pragma unroll
    for (int j = 0; j < 4; ++j)
#pragma unroll
      for (int r = 0; r < 4; ++r)
        eps[(wm * 16 + quad * 4 + r) * 260 + wn * 64 + j * 16 + m16] = acc[i][j][r];
    __syncthreads();
#pragma unroll
    for (int rep = 0; rep < 2; ++rep) {
      const int lr = rep * 16 + (tid >> 5);
      const int rg = m0 + (lr >> 4) * 128 + i * 16 + (lr & 15);
      float v[8];
      *(float4*)(v)     = *(const float4*)(eps + lr * 260 + ecol);
      *(float4*)(v + 4) = *(const float4*)(eps + lr * 260 + ecol + 4);
      if (SCALE_MODE != 0) {
        float rs;
        if (SCALE_MODE == 1) rs = rowscale[rg];
        else                 rs = rsqrtf(rowscale[rg] * (1.0f / D_) + 1e-6f);
#pragma unroll
        for (int e = 0; e < 8; e++) v[e] *= rs;
      }
      if (HAS_BIAS) {
#pragma unroll
        for (int e = 0; e < 8; e++) v[e] += bv[e];
      }
      if (DO_GELU) {
#pragma unroll
        for (int e = 0; e < 8; e++) v[e] = gelu_f(v[e]);
      }
      u16 o[8];
#pragma unroll
      for (int e = 0; e < 8; e++) o[e] = f2bf(v[e]);
      *(uint4*)(C + (size_t)rg * N + n0 + ecol) = *(uint4*)o;
    }
  }
}

// ---- 2-phase bf16 MFMA GEMM (64x128 tiles) for the N=512 GEMMs (proj/ffn2)
// whose 256^2 grids would idle 75% of CUs. Same as round-2 kernel.
template <int BM, int BN, bool HAS_BIAS, int RES_MODE, bool DO_GELU,
          bool STORE_BF16, int SCALE_MODE, bool EMIT_SS>
__global__ __launch_bounds__(256) void gemm_kernel(
    const u16* __restrict__ A, const u16* __restrict__ Bt, void* __restrict__ Cv,
    const float* __restrict__ bias, const void* __restrict__ resv,
    const float* __restrict__ rowscale, float* __restrict__ ssout,
    int M, int N, int K) {
  constexpr int ACH = BM / 32;
  constexpr int BCH = BN / 32;
  constexpr int WM  = BM / 2, WN = BN / 2;
  constexpr int MI  = WM / 16, NJ = WN / 16;
  constexpr int EW  = BN + 4;
  constexpr int STG = (BM + BN) * 128;
  constexpr int EPB = 32 * EW * 4;
  constexpr int SMB = (2 * STG > EPB) ? 2 * STG : EPB;
  __shared__ __align__(16) char smem[SMB];
  const int tid = threadIdx.x;
  const int lane = tid & 63, w = tid >> 6;
  const int quad = lane >> 4, m16 = lane & 15;
  const int wm = w & 1, wn = w >> 1;

  const int nbx  = N / BN;
  const int wg   = blockIdx.x;
  const int xcd  = wg & 7, slot = wg >> 3;
  const int mper = (M / BM) >> 3;
  const int mloc = slot / nbx;
  const int nxp  = slot - mloc * nbx;
  const int m0 = (xcd * mper + mloc) * BM, n0 = nxp * BN;

  f32x4 acc[MI][NJ];
#pragma unroll
  for (int i = 0; i < MI; i++)
#pragma unroll
    for (int j = 0; j < NJ; j++) acc[i][j] = (f32x4){0.f, 0.f, 0.f, 0.f};

  const int srow = tid >> 3;
  const int scol = (((tid & 7) ^ (srow & 7))) * 8;
  const u16* Ag = A  + (size_t)(m0 + srow) * K + scol;
  const u16* Bg = Bt + (size_t)(n0 + srow) * K + scol;

  auto stage = [&](int buf, int kt) {
    char* base = smem + buf * STG;
#pragma unroll
    for (int c = 0; c < ACH; c++)
      async16(Ag + (size_t)c * 32 * K + kt, base + c * 4096 + tid * 16);
#pragma unroll
    for (int c = 0; c < BCH; c++)
      async16(Bg + (size_t)c * 32 * K + kt, base + BM * 128 + c * 4096 + tid * 16);
  };
  auto compute = [&](int buf) {
    const u16* lA = (const u16*)(smem + buf * STG);
    const u16* lB = (const u16*)(smem + buf * STG + BM * 128);
#pragma unroll
    for (int kk = 0; kk < 2; kk++) {
      const int sl = ((kk * 4 + quad) ^ (m16 & 7)) * 8;
      const u16* pa = lA + (wm * WM + m16) * 64 + sl;
      const u16* pb = lB + (wn * WN + m16) * 64 + sl;
      u16x8 af[MI], bfr[NJ];
#pragma unroll
      for (int i = 0; i < MI; i++) af[i] = *(const u16x8*)(pa + i * 1024);
#pragma unroll
      for (int j = 0; j < NJ; j++) bfr[j] = *(const u16x8*)(pb + j * 1024);
#pragma unroll
      for (int i = 0; i < MI; i++)
#pragma unroll
        for (int j = 0; j < NJ; j++)
          acc[i][j] = mfma_bf16(af[i], bfr[j], acc[i][j]);
    }
  };

  const int nk = K >> 6;
  stage(0, 0);
  for (int t = 0; t < nk; t++) {
    __syncthreads();
    if (t + 1 < nk) stage((t + 1) & 1, (t + 1) << 6);
    compute(t & 1);
  }

  float* eps = (float*)smem;
  constexpr int REPS = (32 * BN) / (256 * 8);
  float bv[REPS > 0 ? REPS : 1][8];
  if (HAS_BIAS) {
#pragma unroll
    for (int rep = 0; rep < REPS; rep++) {
      const int col = (BN == 128) ? ((tid & 15) * 8) : ((tid & 7) * 8);
      *(float4*)(bv[rep])     = *(const float4*)(bias + n0 + col);
      *(float4*)(bv[rep] + 4) = *(const float4*)(bias + n0 + col + 4);
    }
  }
#pragma unroll
  for (int i = 0; i < MI; i++) {
    __syncthreads();
#pragma unroll
    for (int j = 0; j < NJ; j++)
#pragma unroll
      for (int r = 0; r < 4; r++)
        eps[(wm * 16 + quad * 4 + r) * EW + wn * WN + j * 16 + m16] =
            acc[i][j][r];
    __syncthreads();
#pragma unroll
    for (int rep = 0; rep < REPS; rep++) {
      const int lr  = (BN == 128) ? (rep * 16 + (tid >> 4)) : (tid >> 3);
      const int col = (BN == 128) ? ((tid & 15) * 8) : ((tid & 7) * 8);
      const int rg  = m0 + (lr >> 4) * WM + i * 16 + (lr & 15);
      float v[8];
      *(float4*)(v)     = *(const float4*)(eps + lr * EW + col);
      *(float4*)(v + 4) = *(const float4*)(eps + lr * EW + col + 4);
      if (SCALE_MODE != 0) {
        float rs;
        if (SCALE_MODE == 1) rs = rowscale[rg];
        else                 rs = rsqrtf(rowscale[rg] * (1.0f / D_) + 1e-6f);
#pragma unroll
        for (int e = 0; e < 8; e++) v[e] *= rs;
      }
      if (HAS_BIAS) {
#pragma unroll
        for (int e = 0; e < 8; e++) v[e] += bv[rep][e];
      }
      if (DO_GELU) {
#pragma unroll
        for (int e = 0; e < 8; e++) v[e] = gelu_f(v[e]);
      }
      const size_t idx = (size_t)rg * N + n0 + col;
      if (RES_MODE == 1) {
        float4 r0 = *(const float4*)((const float*)resv + idx);
        float4 r1 = *(const float4*)((const float*)resv + idx + 4);
        v[0] += r0.x; v[1] += r0.y; v[2] += r0.z; v[3] += r0.w;
        v[4] += r1.x; v[5] += r1.y; v[6] += r1.z; v[7] += r1.w;
      } else if (RES_MODE == 2) {
        u16x8 rr = *(const u16x8*)((const u16*)resv + idx);
#pragma unroll
        for (int e = 0; e < 8; e++) v[e] += bf2f(rr[e]);
      }
      if (EMIT_SS) {
        float ps = 0.f;
#pragma unroll
        for (int e = 0; e < 8; e++) ps += v[e] * v[e];
        ps += __shfl_xor(ps, 1, 64);
        ps += __shfl_xor(ps, 2, 64);
        ps += __shfl_xor(ps, 4, 64);
        ps += __shfl_xor(ps, 8, 64);
        if ((tid & 15) == 0) atomicAdd(ssout + rg, ps);
      }
      if (STORE_BF16) {
        u16 o[8];
#pragma unroll
        for (int e = 0; e < 8; e++) o[e] = f2bf(v[e]);
        *(uint4*)((u16*)Cv + idx) = *(uint4*)o;
      } else {
        *(float4*)((float*)Cv + idx)     = *(float4*)(v);
        *(float4*)((float*)Cv + idx + 4) = *(float4*)(v + 4);
      }
    }
  }
}

// ---- banded attention, MFMA flash-style, full-window softmax in registers.
#define VP_ 216
__global__ __launch_bounds__(256) void attn_kernel(const u16* __restrict__ qkv,
                                                   u16* __restrict__ out) {
  __shared__ __align__(16) char smem[26624 + 64 * VP_ * 2];
  u16* Ks = (u16*)smem;               // [208][64] keys, swizzled (26624 B)
  u16* Vt = (u16*)(smem + 26624);     // [64][216] V transposed (27648 B)
  const int tid = threadIdx.x, lane = tid & 63, w = tid >> 6;
  const int quad = lane >> 4, m16 = lane & 15;
  const int qc = ((blockIdx.x & 7) << 2) | (blockIdx.x >> 3);  // XCD swizzle
  const int q0 = qc * 64, h = blockIdx.y, b = blockIdx.z;
  const int kstart = q0 - 64;         // 208-key staging window
  const u16* base = qkv + (size_t)b * T_ * 1536;

  for (int c = tid; c < 1664; c += 256) {
    int row = c >> 3, ch = c & 7;
    int j = kstart + row;
    j = j < 0 ? 0 : (j > T_ - 1 ? T_ - 1 : j);   // clamp; masked later
    *(uint4*)(Ks + row * 64 + ((ch ^ (row & 7)) * 8)) =
        *(const uint4*)(base + (size_t)j * 1536 + 512 + h * 64 + ch * 8);
  }
  for (int c = tid; c < 1664; c += 256) {
    int row = c >> 3, cc = (c & 7) * 8;
    int j = kstart + row;
    j = j < 0 ? 0 : (j > T_ - 1 ? T_ - 1 : j);
    uint4 u = *(const uint4*)(base + (size_t)j * 1536 + 1024 + h * 64 + cc);
    u16 tmp[8];
    *(uint4*)tmp = u;
#pragma unroll
    for (int i = 0; i < 8; i++) Vt[(cc + i) * VP_ + row] = tmp[i];
  }
  const int qw = q0 + w * 16;
  const u16* qb = base + (size_t)(qw + m16) * 1536 + h * 64 + quad * 8;
  u16x8 a0 = *(const u16x8*)qb;
  u16x8 a1 = *(const u16x8*)(qb + 32);
  __syncthreads();

  float s[10][4];
#pragma unroll
  for (int t = 0; t < 10; t++) {
    int kt = (w + t) * 16;
    int kr = kt + m16, sw = kr & 7;
    u16x8 kb0 = *(const u16x8*)(Ks + kr * 64 + ((quad ^ sw) * 8));
    u16x8 kb1 = *(const u16x8*)(Ks + kr * 64 + (((4 + quad) ^ sw) * 8));
    f32x4 acc = {0.f, 0.f, 0.f, 0.f};
    acc = mfma_bf16(a0, kb0, acc);
    acc = mfma_bf16(a1, kb1, acc);
    int jab = kstart + kt + m16;
#pragma unroll
    for (int r = 0; r < 4; r++) {
      int q = qw + quad * 4 + r;
      int d = q - jab;
      bool valid = (jab >= 0) && (jab < T_) && (d <= 64) && (d >= -64);
      s[t][r] = valid ? acc[r] * 0.125f : -1e30f;
    }
  }
  float mx[4], sm[4];
#pragma unroll
  for (int r = 0; r < 4; r++) mx[r] = -1e30f;
#pragma unroll
  for (int t = 0; t < 10; t++)
#pragma unroll
    for (int r = 0; r < 4; r++) mx[r] = fmaxf(mx[r], s[t][r]);
#pragma unroll
  for (int r = 0; r < 4; r++) {
#pragma unroll
    for (int msk = 1; msk < 16; msk <<= 1)
      mx[r] = fmaxf(mx[r], __shfl_xor(mx[r], msk, 64));
    sm[r] = 0.f;
  }
#pragma unroll
  for (int t = 0; t < 10; t++)
#pragma unroll
    for (int r = 0; r < 4; r++) {
      float e = __expf(s[t][r] - mx[r]);
      s[t][r] = e; sm[r] += e;
    }
#pragma unroll
  for (int r = 0; r < 4; r++) {
#pragma unroll
    for (int msk = 1; msk < 16; msk <<= 1) sm[r] += __shfl_xor(sm[r], msk, 64);
    sm[r] = 1.0f / sm[r];
  }
  __syncthreads();
  u16* Ps = (u16*)smem + w * 2688;       // alias Ks region: per-wave [16][168]
#pragma unroll
  for (int t = 0; t < 10; t++)
#pragma unroll
    for (int r = 0; r < 4; r++)
      Ps[(quad * 4 + r) * 168 + t * 16 + m16] = f2bf(s[t][r] * sm[r]);
  __syncthreads();

  f32x4 o[4];
#pragma unroll
  for (int dt = 0; dt < 4; dt++) o[dt] = (f32x4){0.f, 0.f, 0.f, 0.f};
#pragma unroll
  for (int c5 = 0; c5 < 5; c5++) {
    u16x8 pa = *(const u16x8*)(Ps + m16 * 168 + c5 * 32 + quad * 8);
#pragma unroll
    for (int dt = 0; dt < 4; dt++) {
      u16x8 vb = *(const u16x8*)(Vt + (dt * 16 + m16) * VP_ + w * 16 + c5 * 32 + quad * 8);
      o[dt] = mfma_bf16(pa, vb, o[dt]);
    }
  }
#pragma unroll
  for (int dt = 0; dt < 4; dt++)
#pragma unroll
    for (int r = 0; r < 4; r++)
      out[(size_t)(b * T_ + qw + quad * 4 + r) * D_ + h * HD_ + dt * 16 + m16] =
          f2bf(o[dt][r]);
}

// ---------------------------------------------------------------------------
extern "C" void kernel_launch(void* const* d_in, const int* in_sizes, int n_in,
                              void* d_out, int out_size, void* d_ws, size_t ws_size,
                              hipStream_t stream) {
  (void)in_sizes; (void)n_in; (void)out_size; (void)ws_size;
  const float* x     = (const float*)d_in[0];
  const float* n1w   = (const float*)d_in[1];
  const float* n2w   = (const float*)d_in[2];
  const float* w_qkv = (const float*)d_in[3];
  const float* w_out = (const float*)d_in[4];
  const float* b_out = (const float*)d_in[5];
  const float* w1    = (const float*)d_in[6];
  const float* b1    = (const float*)d_in[7];
  const float* w2    = (const float*)d_in[8];
  const float* b2    = (const float*)d_in[9];
  float* out = (float*)d_out;
  char* ws = (char*)d_ws;

  // workspace layout (hbuf aliases dead qkv+attno)
  u16* wqkvT  = (u16*)(ws + 0);          // [1536][512]  1.5 MB (n1w folded)
  u16* woutT  = (u16*)(ws + 1572864);    // [512][512]   0.5 MB
  u16* w1T    = (u16*)(ws + 2097152);    // [2048][512]  2 MB  (n2w folded)
  u16* w2T    = (u16*)(ws + 4194304);    // [512][2048]  2 MB
  float* inv  = (float*)(ws + 6291456);  // [8192] f32 inv-rms of x
  float* sums = (float*)(ws + 6324224);  // [8192] f32 sumsq of x1 (atomics)
  u16* qkv    = (u16*)(ws + 14680064);   // [8192][1536] 24 MB
  u16* attno  = (u16*)(ws + 39845888);   // [8192][512]  8 MB
  u16* x1     = (u16*)(ws + 48234496);   // [8192][512]  8 MB bf16
  u16* xbf    = (u16*)(ws + 56623104);   // [8192][512]  8 MB bf16 (raw x)
  u16* hbuf   = qkv;                     // [8192][2048] 32 MB (over qkv+attno)

  // raise dynamic-LDS cap for the 128 KB 8-phase kernel (idempotent)
  static bool cfg = false;
  if (!cfg) {
    hipFuncSetAttribute((const void*)gemm256_kernel<false, 1, false>,
                        hipFuncAttributeMaxDynamicSharedMemorySize, 131072);
    hipFuncSetAttribute((const void*)gemm256_kernel<true, 2, true>,
                        hipFuncAttributeMaxDynamicSharedMemorySize, 131072);
    cfg = true;
  }

  // fused: weight transposes (+norm-w fold) + x->bf16 + inv-rms + ss zero
  prep_kernel<<<5152, 256, 0, stream>>>(
      w_qkv, wqkvT, w_out, woutT, w1, w1T, w2, w2T, x, n1w, n2w, inv, xbf, sums);

  // qkv = (x @ [n1w*wqkv]) * inv[row]   (8-phase 256^2, 192 blocks)
  gemm256_kernel<false, 1, false><<<192, 512, 131072, stream>>>(
      xbf, wqkvT, qkv, nullptr, inv, M_, 3 * D_, D_);
  attn_kernel<<<dim3(32, 8, 4), 256, 0, stream>>>(qkv, attno);
  // x1 = attno @ w_out + b_out + xbf ; also emit per-row sumsq(x1) -> sums
  gemm_kernel<64, 128, true, 2, false, true, 0, true>
      <<<dim3(4 * 128), 256, 0, stream>>>(
      attno, woutT, (void*)x1, b_out, xbf, nullptr, sums, M_, D_, D_);
  // hbuf = gelu( (x1 @ [n2w*w1]) * rsqrt(sums/512+eps) + b1 )  (8-phase 256^2)
  gemm256_kernel<true, 2, true><<<256, 512, 131072, stream>>>(
      x1, w1T, hbuf, b1, sums, M_, FF_, D_);
  // out = hbuf @ w2 + b2 + x1   (f32 out, bf16 res)
  gemm_kernel<64, 128, true, 2, false, false, 0, false>
      <<<dim3(4 * 128), 256, 0, stream>>>(
      hbuf, w2T, (void*)out, b2, x1, nullptr, nullptr, M_, D_, FF_);
}

// Round 4
// 196.494 us; speedup vs baseline: 1.0757x; 1.0309x over previous
//
#include <hip/hip_runtime.h>
#include <cstdint>
#include <cstddef>

// ---------------- problem constants (fixed by setup_inputs) ----------------
#define B_  4
#define T_  2048
#define D_  512
#define NH_ 8
#define HD_ 64
#define FF_ 2048
#define M_  (B_*T_)   // 8192 token rows

typedef unsigned short u16;
typedef __attribute__((ext_vector_type(8))) unsigned short u16x8;
typedef __attribute__((ext_vector_type(8))) __bf16         bf16x8;
typedef __attribute__((ext_vector_type(4))) float          f32x4;

__device__ __forceinline__ u16 f2bf(float f) {            // RNE f32 -> bf16
  unsigned u = __float_as_uint(f);
  u += 0x7FFF + ((u >> 16) & 1);
  return (u16)(u >> 16);
}
__device__ __forceinline__ float bf2f(u16 h) {
  return __uint_as_float((unsigned)h << 16);
}

__device__ __forceinline__ f32x4 mfma_bf16(u16x8 a, u16x8 b, f32x4 c) {
  return __builtin_amdgcn_mfma_f32_16x16x32_bf16(
      __builtin_bit_cast(bf16x8, a), __builtin_bit_cast(bf16x8, b), c, 0, 0, 0);
}

// async global->LDS, 16B per lane; LDS dest = wave-uniform base + lane*16
__device__ __forceinline__ void async16(const void* g, void* l) {
  __builtin_amdgcn_global_load_lds(
      (const __attribute__((address_space(1))) unsigned int*)g,
      (__attribute__((address_space(3))) unsigned int*)l, 16, 0, 0);
}

// Branchless GELU via A&S 7.1.26 erf (|err| <= 1.5e-7).
__device__ __forceinline__ float gelu_f(float v) {
  float ax = fabsf(v) * 0.70710678118f;
  float t = 1.0f / (1.0f + 0.3275911f * ax);
  float p = ((((1.061405429f * t - 1.453152027f) * t + 1.421413741f) * t
              - 0.284496736f) * t + 0.254829592f) * t;
  float e = __expf(-ax * ax);
  float er = 1.0f - p * e;
  float s = (v >= 0.0f) ? er : -er;
  return 0.5f * v * (1.0f + s);
}

// ---- fused prep: 4 weight transposes (norm weights FOLDED into wqkv/w1)
// + x->bf16 + per-row inv-rms, in ONE launch.
// blocks 0..3071: transpose tiles; 3072..5119: row pass.
__global__ __launch_bounds__(256) void prep_kernel(
    const float* __restrict__ i0, u16* __restrict__ o0,   // wqkv 512x1536
    const float* __restrict__ i1, u16* __restrict__ o1,   // wout 512x512
    const float* __restrict__ i2, u16* __restrict__ o2,   // w1   512x2048
    const float* __restrict__ i3, u16* __restrict__ o3,   // w2   2048x512
    const float* __restrict__ x, const float* __restrict__ n1w,
    const float* __restrict__ n2w,
    float* __restrict__ inv, u16* __restrict__ xbf) {
  __shared__ float tile[32][33];
  const int bid = blockIdx.x, tid = threadIdx.x;
  if (bid < 3072) {
    const float* in; u16* out; const float* sc; int R, C, gx, lb;
    if (bid < 768)       { in = i0; out = o0; R = 512;  C = 1536; gx = 48; lb = bid;        sc = n1w; }
    else if (bid < 1024) { in = i1; out = o1; R = 512;  C = 512;  gx = 16; lb = bid - 768;  sc = nullptr; }
    else if (bid < 2048) { in = i2; out = o2; R = 512;  C = 2048; gx = 64; lb = bid - 1024; sc = n2w; }
    else                 { in = i3; out = o3; R = 2048; C = 512;  gx = 16; lb = bid - 2048; sc = nullptr; }
    int c0 = (lb % gx) * 32, r0 = (lb / gx) * 32;
    int tx = tid & 31, ty = tid >> 5;  // 32x8
#pragma unroll
    for (int i = 0; i < 4; i++)
      tile[ty + i * 8][tx] = in[(size_t)(r0 + ty + i * 8) * C + c0 + tx];
    __syncthreads();
    float s = sc ? sc[r0 + tx] : 1.0f;   // k-index = r0+tx after transpose
#pragma unroll
    for (int i = 0; i < 4; i++)
      out[(size_t)(c0 + ty + i * 8) * R + r0 + tx] = f2bf(tile[tx][ty + i * 8] * s);
  } else {
    int row  = (bid - 3072) * 4 + (tid >> 6);
    int lane = tid & 63;
    const float* xr = x + (size_t)row * D_ + lane * 8;
    float v[8];
    *(float4*)(v)     = *(const float4*)xr;
    *(float4*)(v + 4) = *(const float4*)(xr + 4);
    u16 rw[8];
#pragma unroll
    for (int e = 0; e < 8; e++) rw[e] = f2bf(v[e]);
    *(uint4*)(xbf + (size_t)row * D_ + lane * 8) = *(uint4*)rw;
    float ss = 0.f;
#pragma unroll
    for (int e = 0; e < 8; e++) ss += v[e] * v[e];
#pragma unroll
    for (int m = 1; m < 64; m <<= 1) ss += __shfl_xor(ss, m, 64);
    if (lane == 0) inv[row] = rsqrtf(ss * (1.0f / D_) + 1e-6f);
  }
}

// ---- 8-phase 256x256 bf16 MFMA GEMM (T3+T4+T5), 512 threads (2Mx4N waves),
// BK=64, 128 KB LDS. Counted vmcnt(4) once per K-tile before the trailing
// barrier; vmcnt(0) only at final drain. setprio(1) around MFMA clusters.
// SCALE_MODE: 0 none, 1 v*=rowscale[rg], 2 rsqrt(rowscale[rg]/512+eps),
//   3 rsqrt((sum of 4 partials rowscale[p*M_+rg])/512+eps)  (fused rmsnorm2).
template <bool HAS_BIAS, int SCALE_MODE, bool DO_GELU>
__global__ __launch_bounds__(512) void gemm256_kernel(
    const u16* __restrict__ A, const u16* __restrict__ Bt, u16* __restrict__ C,
    const float* __restrict__ bias, const float* __restrict__ rowscale,
    int M, int N, int K) {
  extern __shared__ __align__(16) char dsmem[];
  const int tid = threadIdx.x;
  const int lane = tid & 63, w = tid >> 6;
  const int quad = lane >> 4, m16 = lane & 15;
  const int wm = w & 1, wn = w >> 1;         // 2 x 4 wave grid
  // XCD working-set swizzle (bijective; (M/256)%8==0 for all uses)
  const int nbx = N >> 8;
  const int wg  = blockIdx.x;
  const int xcd = wg & 7, slot = wg >> 3;
  const int mper = (M >> 8) >> 3;
  const int mloc = slot / nbx, nxp = slot - mloc * nbx;
  const int m0 = (xcd * mper + mloc) << 8, n0 = nxp << 8;

  const int srow = tid >> 3;                        // 0..63
  const int scol = ((tid & 7) ^ (srow & 7)) * 8;    // swizzled source k-chunk
  const u16* Ag = A  + (size_t)(m0 + srow) * K + scol;
  const u16* Bg = Bt + (size_t)(n0 + srow) * K + scol;

  auto stA = [&](int bsel, int kt, int half) {      // one 128-row half of A
    char* d = dsmem + bsel * 32768 + half * 16384 + tid * 16;
#pragma unroll
    for (int c = 0; c < 2; c++)
      async16(Ag + (size_t)(half * 128 + c * 64) * K + kt * 64, d + c * 8192);
  };
  auto stB = [&](int bsel, int kt, int half) {
    char* d = dsmem + 65536 + bsel * 32768 + half * 16384 + tid * 16;
#pragma unroll
    for (int c = 0; c < 2; c++)
      async16(Bg + (size_t)(half * 128 + c * 64) * K + kt * 64, d + c * 8192);
  };

  f32x4 acc[8][4];
#pragma unroll
  for (int i = 0; i < 8; i++)
#pragma unroll
    for (int j = 0; j < 4; j++) acc[i][j] = (f32x4){0.f, 0.f, 0.f, 0.f};

  const int nk = K >> 6, nt = nk >> 1;
  // prologue: tiles 0 (buf0) and 1 (buf1), then certify tile0 (+barrier)
  stA(0, 0, 0); stA(0, 0, 1); stB(0, 0, 0); stB(0, 0, 1);
  stA(1, 1, 0); stA(1, 1, 1); stB(1, 1, 0); stB(1, 1, 1);
  asm volatile("s_waitcnt vmcnt(8)" ::: "memory");
  __builtin_amdgcn_s_barrier();

  const u16* lA0 = (const u16*)(dsmem);
  const u16* lA1 = (const u16*)(dsmem + 32768);
  const u16* lB0 = (const u16*)(dsmem + 65536);
  const u16* lB1 = (const u16*)(dsmem + 98304);

  for (int t = 0; t < nt; ++t) {
    const int t2 = t << 1;
    const bool last = (t == nt - 1);
    u16x8 bfr[4][2];
    // ---------- phases 0..3 : K-tile t2 (buf0) ----------
#pragma unroll
    for (int q = 0; q < 4; ++q) {
      if (q == 0) {
#pragma unroll
        for (int j = 0; j < 4; ++j)
#pragma unroll
          for (int kk = 0; kk < 2; ++kk)
            bfr[j][kk] = *(const u16x8*)(lB0 + (wn * 64 + j * 16 + m16) * 64 +
                                         (((kk * 4 + quad) ^ (m16 & 7)) * 8));
      }
      u16x8 af[2][2];
#pragma unroll
      for (int s = 0; s < 2; ++s)
#pragma unroll
        for (int kk = 0; kk < 2; ++kk)
          af[s][kk] = *(const u16x8*)(lA0 + (wm * 128 + (q * 2 + s) * 16 + m16) * 64 +
                                      (((kk * 4 + quad) ^ (m16 & 7)) * 8));
      if (q == 0 && t >= 1) stA(1, t2 + 1, 0);
      if (q == 1) {
        if (t >= 1) stA(1, t2 + 1, 1);
        if (t2 + 2 < nk) stB(0, t2 + 2, 0);
      }
      if (q == 2 && t2 + 2 < nk) stB(0, t2 + 2, 1);
      __builtin_amdgcn_s_barrier();
      asm volatile("s_waitcnt lgkmcnt(0)" ::: "memory");
      __builtin_amdgcn_s_setprio(1);
#pragma unroll
      for (int s = 0; s < 2; ++s)
#pragma unroll
        for (int kk = 0; kk < 2; ++kk)
#pragma unroll
          for (int j = 0; j < 4; ++j)
            acc[q * 2 + s][j] = mfma_bf16(af[s][kk], bfr[j][kk], acc[q * 2 + s][j]);
      __builtin_amdgcn_s_setprio(0);
      if (q == 3) {                 // certify buf1 K-tile t2+1 before ph4 reads
        if (last) asm volatile("s_waitcnt vmcnt(0)" ::: "memory");
        else      asm volatile("s_waitcnt vmcnt(4)" ::: "memory");
      }
      __builtin_amdgcn_s_barrier();
    }
    // ---------- phases 4..7 : K-tile t2+1 (buf1) ----------
#pragma unroll
    for (int q = 0; q < 4; ++q) {
      if (q == 0) {
#pragma unroll
        for (int j = 0; j < 4; ++j)
#pragma unroll
          for (int kk = 0; kk < 2; ++kk)
            bfr[j][kk] = *(const u16x8*)(lB1 + (wn * 64 + j * 16 + m16) * 64 +
                                         (((kk * 4 + quad) ^ (m16 & 7)) * 8));
      }
      u16x8 af[2][2];
#pragma unroll
      for (int s = 0; s < 2; ++s)
#pragma unroll
        for (int kk = 0; kk < 2; ++kk)
          af[s][kk] = *(const u16x8*)(lA1 + (wm * 128 + (q * 2 + s) * 16 + m16) * 64 +
                                      (((kk * 4 + quad) ^ (m16 & 7)) * 8));
      if (q == 0 && t2 + 2 < nk) stA(0, t2 + 2, 0);
      if (q == 1) {
        if (t2 + 2 < nk) stA(0, t2 + 2, 1);
        if (t2 + 3 < nk) stB(1, t2 + 3, 0);
      }
      if (q == 2 && t2 + 3 < nk) stB(1, t2 + 3, 1);
      __builtin_amdgcn_s_barrier();
      asm volatile("s_waitcnt lgkmcnt(0)" ::: "memory");
      __builtin_amdgcn_s_setprio(1);
#pragma unroll
      for (int s = 0; s < 2; ++s)
#pragma unroll
        for (int kk = 0; kk < 2; ++kk)
#pragma unroll
          for (int j = 0; j < 4; ++j)
            acc[q * 2 + s][j] = mfma_bf16(af[s][kk], bfr[j][kk], acc[q * 2 + s][j]);
      __builtin_amdgcn_s_setprio(0);
      if (q == 3 && !last)          // certify buf0 K-tile t2+2 before next iter
        asm volatile("s_waitcnt vmcnt(4)" ::: "memory");
      __builtin_amdgcn_s_barrier();
    }
  }

  // ---- epilogue: per i-step stage 32 rows x 256 cols f32 in LDS (pitch 260),
  // read back row-major, apply scale/bias/gelu, store bf16.
  __syncthreads();
  float* eps = (float*)dsmem;
  const int ecol = (tid & 31) * 8;
  float bv[8];
  if (HAS_BIAS) {
    *(float4*)(bv)     = *(const float4*)(bias + n0 + ecol);
    *(float4*)(bv + 4) = *(const float4*)(bias + n0 + ecol + 4);
  }
#pragma unroll
  for (int i = 0; i < 8; ++i) {
    __syncthreads();
#pragma unroll
    for (int j = 0; j < 4; ++j)
#pragma unroll
      for (int r = 0; r < 4; ++r)
        eps[(wm * 16 + quad * 4 + r) * 260 + wn * 64 + j * 16 + m16] = acc[i][j][r];
    __syncthreads();
#pragma unroll
    for (int rep = 0; rep < 2; ++rep) {
      const int lr = rep * 16 + (tid >> 5);
      const int rg = m0 + (lr >> 4) * 128 + i * 16 + (lr & 15);
      float v[8];
      *(float4*)(v)     = *(const float4*)(eps + lr * 260 + ecol);
      *(float4*)(v + 4) = *(const float4*)(eps + lr * 260 + ecol + 4);
      if (SCALE_MODE != 0) {
        float rs;
        if (SCALE_MODE == 1)      rs = rowscale[rg];
        else if (SCALE_MODE == 2) rs = rsqrtf(rowscale[rg] * (1.0f / D_) + 1e-6f);
        else {
          float s4 = rowscale[rg] + rowscale[M_ + rg] +
                     rowscale[2 * M_ + rg] + rowscale[3 * M_ + rg];
          rs = rsqrtf(s4 * (1.0f / D_) + 1e-6f);
        }
#pragma unroll
        for (int e = 0; e < 8; e++) v[e] *= rs;
      }
      if (HAS_BIAS) {
#pragma unroll
        for (int e = 0; e < 8; e++) v[e] += bv[e];
      }
      if (DO_GELU) {
#pragma unroll
        for (int e = 0; e < 8; e++) v[e] = gelu_f(v[e]);
      }
      u16 o[8];
#pragma unroll
      for (int e = 0; e < 8; e++) o[e] = f2bf(v[e]);
      *(uint4*)(C + (size_t)rg * N + n0 + ecol) = *(uint4*)o;
    }
  }
}

// ---- 2-phase bf16 MFMA GEMM (64x128 tiles) with COUNTED vmcnt (T4):
// per K-step: [barrier from prev iter] -> issue stage(t+1) -> vmcnt(6)
// (stage(t) certified, stage(t+1) stays in flight through compute) ->
// barrier (globalize) -> compute(t) -> trailing barrier (overwrite safety).
// EMIT_SS: per-row partial sumsq of FINAL value -> plain store to
// ssout[nxp*M + rg] (no atomics; consumer sums the n-panels).
template <int BM, int BN, bool HAS_BIAS, int RES_MODE, bool DO_GELU,
          bool STORE_BF16, int SCALE_MODE, bool EMIT_SS>
__global__ __launch_bounds__(256) void gemm_kernel(
    const u16* __restrict__ A, const u16* __restrict__ Bt, void* __restrict__ Cv,
    const float* __restrict__ bias, const void* __restrict__ resv,
    const float* __restrict__ rowscale, float* __restrict__ ssout,
    int M, int N, int K) {
  constexpr int ACH = BM / 32;
  constexpr int BCH = BN / 32;
  constexpr int WM  = BM / 2, WN = BN / 2;
  constexpr int MI  = WM / 16, NJ = WN / 16;
  constexpr int EW  = BN + 4;
  constexpr int STG = (BM + BN) * 128;
  constexpr int EPB = 32 * EW * 4;
  constexpr int SMB = (2 * STG > EPB) ? 2 * STG : EPB;
  static_assert(ACH + BCH == 6, "vmcnt literal assumes 6 loads per stage");
  __shared__ __align__(16) char smem[SMB];
  const int tid = threadIdx.x;
  const int lane = tid & 63, w = tid >> 6;
  const int quad = lane >> 4, m16 = lane & 15;
  const int wm = w & 1, wn = w >> 1;

  const int nbx  = N / BN;
  const int wg   = blockIdx.x;
  const int xcd  = wg & 7, slot = wg >> 3;
  const int mper = (M / BM) >> 3;
  const int mloc = slot / nbx;
  const int nxp  = slot - mloc * nbx;
  const int m0 = (xcd * mper + mloc) * BM, n0 = nxp * BN;

  f32x4 acc[MI][NJ];
#pragma unroll
  for (int i = 0; i < MI; i++)
#pragma unroll
    for (int j = 0; j < NJ; j++) acc[i][j] = (f32x4){0.f, 0.f, 0.f, 0.f};

  const int srow = tid >> 3;
  const int scol = (((tid & 7) ^ (srow & 7))) * 8;
  const u16* Ag = A  + (size_t)(m0 + srow) * K + scol;
  const u16* Bg = Bt + (size_t)(n0 + srow) * K + scol;

  auto stage = [&](int buf, int kt) {
    char* base = smem + buf * STG;
#pragma unroll
    for (int c = 0; c < ACH; c++)
      async16(Ag + (size_t)c * 32 * K + kt, base + c * 4096 + tid * 16);
#pragma unroll
    for (int c = 0; c < BCH; c++)
      async16(Bg + (size_t)c * 32 * K + kt, base + BM * 128 + c * 4096 + tid * 16);
  };
  auto compute = [&](int buf) {
    const u16* lA = (const u16*)(smem + buf * STG);
    const u16* lB = (const u16*)(smem + buf * STG + BM * 128);
#pragma unroll
    for (int kk = 0; kk < 2; kk++) {
      const int sl = ((kk * 4 + quad) ^ (m16 & 7)) * 8;
      const u16* pa = lA + (wm * WM + m16) * 64 + sl;
      const u16* pb = lB + (wn * WN + m16) * 64 + sl;
      u16x8 af[MI], bfr[NJ];
#pragma unroll
      for (int i = 0; i < MI; i++) af[i] = *(const u16x8*)(pa + i * 1024);
#pragma unroll
      for (int j = 0; j < NJ; j++) bfr[j] = *(const u16x8*)(pb + j * 1024);
#pragma unroll
      for (int i = 0; i < MI; i++)
#pragma unroll
        for (int j = 0; j < NJ; j++)
          acc[i][j] = mfma_bf16(af[i], bfr[j], acc[i][j]);
    }
  };

  const int nk = K >> 6;
  stage(0, 0);
  for (int t = 0; t < nk; t++) {
    if (t + 1 < nk) {
      stage((t + 1) & 1, (t + 1) << 6);           // 6 loads, stay in flight
      asm volatile("s_waitcnt vmcnt(6)" ::: "memory");   // stage(t) done (wave)
    } else {
      asm volatile("s_waitcnt vmcnt(0)" ::: "memory");   // final drain
    }
    __builtin_amdgcn_s_barrier();                 // globalize stage(t)
    compute(t & 1);
    __builtin_amdgcn_s_barrier();                 // reads done before overwrite
  }

  float* eps = (float*)smem;
  constexpr int REPS = (32 * BN) / (256 * 8);
  float bv[REPS > 0 ? REPS : 1][8];
  if (HAS_BIAS) {
#pragma unroll
    for (int rep = 0; rep < REPS; rep++) {
      const int col = (BN == 128) ? ((tid & 15) * 8) : ((tid & 7) * 8);
      *(float4*)(bv[rep])     = *(const float4*)(bias + n0 + col);
      *(float4*)(bv[rep] + 4) = *(const float4*)(bias + n0 + col + 4);
    }
  }
#pragma unroll
  for (int i = 0; i < MI; i++) {
    __syncthreads();
#pragma unroll
    for (int j = 0; j < NJ; j++)
#pragma unroll
      for (int r = 0; r < 4; r++)
        eps[(wm * 16 + quad * 4 + r) * EW + wn * WN + j * 16 + m16] =
            acc[i][j][r];
    __syncthreads();
#pragma unroll
    for (int rep = 0; rep < REPS; rep++) {
      const int lr  = (BN == 128) ? (rep * 16 + (tid >> 4)) : (tid >> 3);
      const int col = (BN == 128) ? ((tid & 15) * 8) : ((tid & 7) * 8);
      const int rg  = m0 + (lr >> 4) * WM + i * 16 + (lr & 15);
      float v[8];
      *(float4*)(v)     = *(const float4*)(eps + lr * EW + col);
      *(float4*)(v + 4) = *(const float4*)(eps + lr * EW + col + 4);
      if (SCALE_MODE != 0) {
        float rs;
        if (SCALE_MODE == 1) rs = rowscale[rg];
        else                 rs = rsqrtf(rowscale[rg] * (1.0f / D_) + 1e-6f);
#pragma unroll
        for (int e = 0; e < 8; e++) v[e] *= rs;
      }
      if (HAS_BIAS) {
#pragma unroll
        for (int e = 0; e < 8; e++) v[e] += bv[rep][e];
      }
      if (DO_GELU) {
#pragma unroll
        for (int e = 0; e < 8; e++) v[e] = gelu_f(v[e]);
      }
      const size_t idx = (size_t)rg * N + n0 + col;
      if (RES_MODE == 1) {
        float4 r0 = *(const float4*)((const float*)resv + idx);
        float4 r1 = *(const float4*)((const float*)resv + idx + 4);
        v[0] += r0.x; v[1] += r0.y; v[2] += r0.z; v[3] += r0.w;
        v[4] += r1.x; v[5] += r1.y; v[6] += r1.z; v[7] += r1.w;
      } else if (RES_MODE == 2) {
        u16x8 rr = *(const u16x8*)((const u16*)resv + idx);
#pragma unroll
        for (int e = 0; e < 8; e++) v[e] += bf2f(rr[e]);
      }
      if (EMIT_SS) {   // per-row partial sumsq (16 threads per row), no atomics
        float ps = 0.f;
#pragma unroll
        for (int e = 0; e < 8; e++) ps += v[e] * v[e];
        ps += __shfl_xor(ps, 1, 64);
        ps += __shfl_xor(ps, 2, 64);
        ps += __shfl_xor(ps, 4, 64);
        ps += __shfl_xor(ps, 8, 64);
        if ((tid & 15) == 0) ssout[(size_t)nxp * M + rg] = ps;
      }
      if (STORE_BF16) {
        u16 o[8];
#pragma unroll
        for (int e = 0; e < 8; e++) o[e] = f2bf(v[e]);
        *(uint4*)((u16*)Cv + idx) = *(uint4*)o;
      } else {
        *(float4*)((float*)Cv + idx)     = *(float4*)(v);
        *(float4*)((float*)Cv + idx + 4) = *(float4*)(v + 4);
      }
    }
  }
}

// ---- banded attention, MFMA flash-style, full-window softmax in registers.
// K staged via global_load_lds (pre-swizzled per-lane SOURCE, linear LDS dest;
// __syncthreads' vmcnt(0) certifies). V transposed manually (unchanged).
#define VP_ 216
__global__ __launch_bounds__(256) void attn_kernel(const u16* __restrict__ qkv,
                                                   u16* __restrict__ out) {
  __shared__ __align__(16) char smem[26624 + 64 * VP_ * 2];
  u16* Ks = (u16*)smem;               // [208][64] keys, swizzled (26624 B)
  u16* Vt = (u16*)(smem + 26624);     // [64][216] V transposed (27648 B)
  const int tid = threadIdx.x, lane = tid & 63, w = tid >> 6;
  const int quad = lane >> 4, m16 = lane & 15;
  const int qc = ((blockIdx.x & 7) << 2) | (blockIdx.x >> 3);  // XCD swizzle
  const int q0 = qc * 64, h = blockIdx.y, b = blockIdx.z;
  const int kstart = q0 - 64;         // 208-key staging window
  const u16* base = qkv + (size_t)b * T_ * 1536;

  // K: 1664 16B chunks = 6*256 + 128; dest linear, source swizzled so that
  // LDS slot s of row r holds chunk s^(r&7) (same involution as before).
#pragma unroll
  for (int r6 = 0; r6 < 6; r6++) {
    int c = r6 * 256 + tid;
    int row = c >> 3;
    int j = kstart + row;
    j = j < 0 ? 0 : (j > T_ - 1 ? T_ - 1 : j);
    int srcch = ((c & 7) ^ (row & 7)) * 8;
    async16(base + (size_t)j * 1536 + 512 + h * 64 + srcch, smem + c * 16);
  }
  if (tid < 128) {
    int c = 1536 + tid;
    int row = c >> 3;
    int j = kstart + row;
    j = j < 0 ? 0 : (j > T_ - 1 ? T_ - 1 : j);
    int srcch = ((c & 7) ^ (row & 7)) * 8;
    async16(base + (size_t)j * 1536 + 512 + h * 64 + srcch, smem + c * 16);
  }
  for (int c = tid; c < 1664; c += 256) {
    int row = c >> 3, cc = (c & 7) * 8;
    int j = kstart + row;
    j = j < 0 ? 0 : (j > T_ - 1 ? T_ - 1 : j);
    uint4 u = *(const uint4*)(base + (size_t)j * 1536 + 1024 + h * 64 + cc);
    u16 tmp[8];
    *(uint4*)tmp = u;
#pragma unroll
    for (int i = 0; i < 8; i++) Vt[(cc + i) * VP_ + row] = tmp[i];
  }
  const int qw = q0 + w * 16;
  const u16* qb = base + (size_t)(qw + m16) * 1536 + h * 64 + quad * 8;
  u16x8 a0 = *(const u16x8*)qb;
  u16x8 a1 = *(const u16x8*)(qb + 32);
  __syncthreads();

  float s[10][4];
#pragma unroll
  for (int t = 0; t < 10; t++) {
    int kt = (w + t) * 16;
    int kr = kt + m16, sw = kr & 7;
    u16x8 kb0 = *(const u16x8*)(Ks + kr * 64 + ((quad ^ sw) * 8));
    u16x8 kb1 = *(const u16x8*)(Ks + kr * 64 + (((4 + quad) ^ sw) * 8));
    f32x4 acc = {0.f, 0.f, 0.f, 0.f};
    acc = mfma_bf16(a0, kb0, acc);
    acc = mfma_bf16(a1, kb1, acc);
    int jab = kstart + kt + m16;
#pragma unroll
    for (int r = 0; r < 4; r++) {
      int q = qw + quad * 4 + r;
      int d = q - jab;
      bool valid = (jab >= 0) && (jab < T_) && (d <= 64) && (d >= -64);
      s[t][r] = valid ? acc[r] * 0.125f : -1e30f;
    }
  }
  float mx[4], sm[4];
#pragma unroll
  for (int r = 0; r < 4; r++) mx[r] = -1e30f;
#pragma unroll
  for (int t = 0; t < 10; t++)
#pragma unroll
    for (int r = 0; r < 4; r++) mx[r] = fmaxf(mx[r], s[t][r]);
#pragma unroll
  for (int r = 0; r < 4; r++) {
#pragma unroll
    for (int msk = 1; msk < 16; msk <<= 1)
      mx[r] = fmaxf(mx[r], __shfl_xor(mx[r], msk, 64));
    sm[r] = 0.f;
  }
#pragma unroll
  for (int t = 0; t < 10; t++)
#pragma unroll
    for (int r = 0; r < 4; r++) {
      float e = __expf(s[t][r] - mx[r]);
      s[t][r] = e; sm[r] += e;
    }
#pragma unroll
  for (int r = 0; r < 4; r++) {
#pragma unroll
    for (int msk = 1; msk < 16; msk <<= 1) sm[r] += __shfl_xor(sm[r], msk, 64);
    sm[r] = 1.0f / sm[r];
  }
  __syncthreads();
  u16* Ps = (u16*)smem + w * 2688;       // alias Ks region: per-wave [16][168]
#pragma unroll
  for (int t = 0; t < 10; t++)
#pragma unroll
    for (int r = 0; r < 4; r++)
      Ps[(quad * 4 + r) * 168 + t * 16 + m16] = f2bf(s[t][r] * sm[r]);
  __syncthreads();

  f32x4 o[4];
#pragma unroll
  for (int dt = 0; dt < 4; dt++) o[dt] = (f32x4){0.f, 0.f, 0.f, 0.f};
#pragma unroll
  for (int c5 = 0; c5 < 5; c5++) {
    u16x8 pa = *(const u16x8*)(Ps + m16 * 168 + c5 * 32 + quad * 8);
#pragma unroll
    for (int dt = 0; dt < 4; dt++) {
      u16x8 vb = *(const u16x8*)(Vt + (dt * 16 + m16) * VP_ + w * 16 + c5 * 32 + quad * 8);
      o[dt] = mfma_bf16(pa, vb, o[dt]);
    }
  }
#pragma unroll
  for (int dt = 0; dt < 4; dt++)
#pragma unroll
    for (int r = 0; r < 4; r++)
      out[(size_t)(b * T_ + qw + quad * 4 + r) * D_ + h * HD_ + dt * 16 + m16] =
          f2bf(o[dt][r]);
}

// ---------------------------------------------------------------------------
extern "C" void kernel_launch(void* const* d_in, const int* in_sizes, int n_in,
                              void* d_out, int out_size, void* d_ws, size_t ws_size,
                              hipStream_t stream) {
  (void)in_sizes; (void)n_in; (void)out_size; (void)ws_size;
  const float* x     = (const float*)d_in[0];
  const float* n1w   = (const float*)d_in[1];
  const float* n2w   = (const float*)d_in[2];
  const float* w_qkv = (const float*)d_in[3];
  const float* w_out = (const float*)d_in[4];
  const float* b_out = (const float*)d_in[5];
  const float* w1    = (const float*)d_in[6];
  const float* b1    = (const float*)d_in[7];
  const float* w2    = (const float*)d_in[8];
  const float* b2    = (const float*)d_in[9];
  float* out = (float*)d_out;
  char* ws = (char*)d_ws;

  // workspace layout (hbuf aliases dead qkv+attno)
  u16* wqkvT  = (u16*)(ws + 0);          // [1536][512]  1.5 MB (n1w folded)
  u16* woutT  = (u16*)(ws + 1572864);    // [512][512]   0.5 MB
  u16* w1T    = (u16*)(ws + 2097152);    // [2048][512]  2 MB  (n2w folded)
  u16* w2T    = (u16*)(ws + 4194304);    // [512][2048]  2 MB
  float* inv  = (float*)(ws + 6291456);  // [8192] f32 inv-rms of x
  float* sums4= (float*)(ws + 6324224);  // [4][8192] f32 partial sumsq of x1
  u16* qkv    = (u16*)(ws + 14680064);   // [8192][1536] 24 MB
  u16* attno  = (u16*)(ws + 39845888);   // [8192][512]  8 MB
  u16* x1     = (u16*)(ws + 48234496);   // [8192][512]  8 MB bf16
  u16* xbf    = (u16*)(ws + 56623104);   // [8192][512]  8 MB bf16 (raw x)
  u16* hbuf   = qkv;                     // [8192][2048] 32 MB (over qkv+attno)

  // raise dynamic-LDS cap for the 128 KB 8-phase kernel (idempotent)
  static bool cfg = false;
  if (!cfg) {
    hipFuncSetAttribute((const void*)gemm256_kernel<false, 1, false>,
                        hipFuncAttributeMaxDynamicSharedMemorySize, 131072);
    hipFuncSetAttribute((const void*)gemm256_kernel<true, 3, true>,
                        hipFuncAttributeMaxDynamicSharedMemorySize, 131072);
    cfg = true;
  }

  // fused: weight transposes (+norm-w fold) + x->bf16 + inv-rms
  prep_kernel<<<5120, 256, 0, stream>>>(
      w_qkv, wqkvT, w_out, woutT, w1, w1T, w2, w2T, x, n1w, n2w, inv, xbf);

  // qkv = (x @ [n1w*wqkv]) * inv[row]   (8-phase 256^2, 192 blocks)
  gemm256_kernel<false, 1, false><<<192, 512, 131072, stream>>>(
      xbf, wqkvT, qkv, nullptr, inv, M_, 3 * D_, D_);
  attn_kernel<<<dim3(32, 8, 4), 256, 0, stream>>>(qkv, attno);
  // x1 = attno @ w_out + b_out + xbf ; emit per-row partial sumsq -> sums4
  gemm_kernel<64, 128, true, 2, false, true, 0, true>
      <<<dim3(4 * 128), 256, 0, stream>>>(
      attno, woutT, (void*)x1, b_out, xbf, nullptr, sums4, M_, D_, D_);
  // hbuf = gelu( (x1 @ [n2w*w1]) * rsqrt(sum4(sums4)/512+eps) + b1 )
  gemm256_kernel<true, 3, true><<<256, 512, 131072, stream>>>(
      x1, w1T, hbuf, b1, sums4, M_, FF_, D_);
  // out = hbuf @ w2 + b2 + x1   (f32 out, bf16 res)
  gemm_kernel<64, 128, true, 2, false, false, 0, false>
      <<<dim3(4 * 128), 256, 0, stream>>>(
      hbuf, w2T, (void*)out, b2, x1, nullptr, nullptr, M_, D_, FF_);
}